// Round 2
// baseline (236.229 us; speedup 1.0000x reference)
//
#include <hip/hip_runtime.h>
#include <math.h>

// Problem constants
#define NHEADS   64
#define TLEN     4096
#define CHUNK    16
#define NCHUNK   256  // TLEN / CHUNK

// ws layout (float offsets)
//  Pm    : 0        (64*8*8 = 4096)
//  gamma : 4096     (64)
//  theta : 4160     (256)
//  norm  : 4416     (64)
//  W1T   : 8192     (512*512)    W1T[d][k] : U = X^T @ W1T
//  CET   : 270336   (512*512)    CET[k][e]
//  U/H   : 532480   (4096*512)   state sequence (local scan only; fixup fused into out-GEMM)
//  E     : 2629632  (256*512)    chunk-local end states
//  S     : 2760704  (256*512)    carry state into each chunk
//  TAB   : 2891776  (16*256*2)   gamma^{i+1}*cos/sin((i+1)theta) per (i, pair)
// total: 2899968 floats = 11.6 MB

// ---------------------------------------------------------------------------
// Kernel 1: per-head params + expm(P - P^T) via scaling-and-squaring Taylor.
// One block per head, 64 threads = one per 8x8 matrix element. fp64 internal.
__global__ void k_setup(const float* __restrict__ P,
                        const float* __restrict__ Bmat,
                        const float* __restrict__ theta_log,
                        const float* __restrict__ gamma_log,
                        float* __restrict__ ws) {
    __shared__ double As[8][8];
    __shared__ double Rs[8][8];
    __shared__ double red[64];
    __shared__ int sh_s;
    const int h = blockIdx.x;
    const int tid = threadIdx.x;
    const int i = tid >> 3, j = tid & 7;

    // skew-symmetric part
    As[i][j] = (double)P[(h*8 + i)*8 + j] - (double)P[(h*8 + j)*8 + i];

    // trace(B B^T) for this head: sum of squares of 8x512 block (coalesced)
    const float* Bh = Bmat + h*8*512;
    double ss = 0.0;
    for (int q = 0; q < 64; ++q) { float v = Bh[q*64 + tid]; ss += (double)v * (double)v; }
    red[tid] = ss;
    __syncthreads();

    if (tid == 0) {
        double nrm = 0.0;
        for (int r = 0; r < 8; ++r) {
            double rs = 0.0;
            for (int c = 0; c < 8; ++c) rs += fabs(As[r][c]);
            nrm = fmax(nrm, rs);
        }
        int s = 0;
        while (nrm > 0.25 && s < 40) { nrm *= 0.5; ++s; }
        sh_s = s;
        double tr = 0.0;
        for (int q = 0; q < 64; ++q) tr += red[q];
        double ed = exp((double)gamma_log[h]);
        double g  = exp(-ed);
        ws[4096 + h] = (float)g;
        ws[4416 + h] = (float)sqrt((1.0 - g*g) / tr);
    }
    if (tid < 4) ws[4160 + h*4 + tid] = expf(theta_log[h*4 + tid]);
    __syncthreads();

    const double sc = ldexp(1.0, -sh_s);
    As[i][j] *= sc;                      // own element only
    const int NT = 13;
    Rs[i][j] = (i == j ? 1.0 : 0.0) + As[i][j] / (double)NT;
    __syncthreads();
    for (int k = NT - 1; k >= 1; --k) {
        double t = 0.0;
        #pragma unroll
        for (int m = 0; m < 8; ++m) t += As[i][m] * Rs[m][j];
        __syncthreads();
        Rs[i][j] = (i == j ? 1.0 : 0.0) + t / (double)k;
        __syncthreads();
    }
    for (int q = 0; q < sh_s; ++q) {
        double t = 0.0;
        #pragma unroll
        for (int m = 0; m < 8; ++m) t += Rs[i][m] * Rs[m][j];
        __syncthreads();
        Rs[i][j] = t;
        __syncthreads();
    }
    ws[h*64 + i*8 + j] = (float)Rs[i][j];
}

// ---------------------------------------------------------------------------
// Kernel 2 (merged): first 262144 items -> W1T, next 262144 -> CET.
//  W1T[d][k] = norm[h] * sum_n Pm[h][N][n] * B[(h*8+n)][d],  k = h*8+N
//  CET[k][e] = sum_n C[e][h*8+n] * Pm[h][N][n]
__global__ void k_proj(const float* __restrict__ Bmat,
                       const float* __restrict__ C,
                       const float* __restrict__ ws_ro,
                       float* __restrict__ W1T,
                       float* __restrict__ CET) {
    const int gid = blockIdx.x * 256 + threadIdx.x;
    if (gid < 512*512) {
        const int d = gid >> 9, k = gid & 511;
        const int h = k >> 3, N = k & 7;
        const float* Pm = ws_ro + h*64 + N*8;
        const float nrm = ws_ro[4416 + h];
        float acc = 0.f;
        #pragma unroll
        for (int n = 0; n < 8; ++n) acc += Pm[n] * Bmat[(h*8 + n)*512 + d];
        W1T[d*512 + k] = nrm * acc;
    } else {
        const int g2 = gid - 512*512;
        const int e = g2 & 511, k = g2 >> 9;
        const int h = k >> 3, N = k & 7;
        const float* Pm = ws_ro + h*64 + N*8;
        float acc = 0.f;
        #pragma unroll
        for (int n = 0; n < 8; ++n) acc += Pm[n] * C[e*512 + h*8 + n];
        CET[k*512 + e] = acc;
    }
}

// ---------------------------------------------------------------------------
// Kernel 3: U[t][k] = sum_d X[d][t] * W1T[d][k]   (M=4096, N=512, K=512)
// X is [d][t] in memory (t contiguous) — already K-major for A.
__global__ __launch_bounds__(256) void k_gemm_u(const float* __restrict__ X,
                                                const float* __restrict__ W1T,
                                                float* __restrict__ U) {
    __shared__ float As[16][128];
    __shared__ float Bs[16][64];
    const int tid = threadIdx.x;
    const int tx = tid & 15, ty = tid >> 4;
    const int t0 = blockIdx.y * 128, k0 = blockIdx.x * 64;
    float acc[8][4] = {};
    for (int d0 = 0; d0 < 512; d0 += 16) {
        #pragma unroll
        for (int r = 0; r < 2; ++r) {
            int f = tid + r*256;
            int dd = f >> 5, mm4 = f & 31;
            float4 v = *reinterpret_cast<const float4*>(X + (d0 + dd)*4096 + t0 + mm4*4);
            *reinterpret_cast<float4*>(&As[dd][mm4*4]) = v;
        }
        {
            int dd = tid >> 4, kk4 = tid & 15;
            float4 v = *reinterpret_cast<const float4*>(W1T + (d0 + dd)*512 + k0 + kk4*4);
            *reinterpret_cast<float4*>(&Bs[dd][kk4*4]) = v;
        }
        __syncthreads();
        #pragma unroll
        for (int kk = 0; kk < 16; ++kk) {
            float a[8], b[4];
            *reinterpret_cast<float4*>(a)     = *reinterpret_cast<const float4*>(&As[kk][ty*8]);
            *reinterpret_cast<float4*>(a + 4) = *reinterpret_cast<const float4*>(&As[kk][ty*8 + 4]);
            *reinterpret_cast<float4*>(b)     = *reinterpret_cast<const float4*>(&Bs[kk][tx*4]);
            #pragma unroll
            for (int ii = 0; ii < 8; ++ii)
                #pragma unroll
                for (int jj = 0; jj < 4; ++jj)
                    acc[ii][jj] = fmaf(a[ii], b[jj], acc[ii][jj]);
        }
        __syncthreads();
    }
    #pragma unroll
    for (int ii = 0; ii < 8; ++ii) {
        float4 v = make_float4(acc[ii][0], acc[ii][1], acc[ii][2], acc[ii][3]);
        *reinterpret_cast<float4*>(U + (t0 + ty*8 + ii)*512 + k0 + tx*4) = v;
    }
}

// ---------------------------------------------------------------------------
// Kernel 4: per-chunk local scan, in place.  h_t = g*R(theta)*h_{t-1} + u_t
// 256 blocks (one per chunk) x 256 threads (one per rotation pair).
__global__ void k_scan_local(float* __restrict__ U, float* __restrict__ E,
                             const float* __restrict__ ws_ro) {
    const int c = blockIdx.x;
    const int p = threadIdx.x;                 // pair 0..255, state dims (2p, 2p+1)
    const float th = ws_ro[4160 + p];
    const float g  = ws_ro[4096 + (p >> 2)];
    const float cs = cosf(th), sn = sinf(th);
    float h0 = 0.f, h1 = 0.f;
    const int base = c * CHUNK;
    #pragma unroll
    for (int i = 0; i < CHUNK; ++i) {
        float2* ptr = reinterpret_cast<float2*>(U + (base + i)*512 + 2*p);
        float2 u = *ptr;
        float n0 = g*(cs*h0 - sn*h1) + u.x;
        float n1 = g*(sn*h0 + cs*h1) + u.y;
        *ptr = make_float2(n0, n1);
        h0 = n0; h1 = n1;
    }
    E[c*512 + 2*p]     = h0;
    E[c*512 + 2*p + 1] = h1;
}

// Kernel 5: sequential carry over chunk ends + fix-up coefficient table.
// S[c] = true state at end of chunk c-1; S[0] = 0.
__global__ void k_carry(const float* __restrict__ E, float* __restrict__ S,
                        float* __restrict__ TAB,
                        const float* __restrict__ theta_log,
                        const float* __restrict__ gamma_log) {
    const int p = threadIdx.x;                 // 0..255
    const double th = exp((double)theta_log[p]);
    const double ed = exp((double)gamma_log[p >> 2]);
    const double g  = exp(-ed);
    const double cd = cos(th), sd = sin(th);
    // gc,gs = gamma^{i+1} * (cos,sin)((i+1)*theta) via exact rotation recurrence
    double gc = g*cd, gs = g*sd;
    for (int i = 0; i < CHUNK; ++i) {
        if (i) {
            double t0 = g*(cd*gc - sd*gs);
            double t1 = g*(sd*gc + cd*gs);
            gc = t0; gs = t1;
        }
        TAB[(i*256 + p)*2 + 0] = (float)gc;
        TAB[(i*256 + p)*2 + 1] = (float)gs;
    }
    // now (gc,gs) = gamma^CHUNK * (cos,sin)(CHUNK*theta): the chunk-step operator
    const float fLc = (float)gc, fLs = (float)gs;
    float s0 = 0.f, s1 = 0.f;
    S[2*p] = 0.f; S[2*p + 1] = 0.f;
    for (int c = 1; c < NCHUNK; ++c) {
        float e0 = E[(c-1)*512 + 2*p], e1 = E[(c-1)*512 + 2*p + 1];
        float n0 = fLc*s0 - fLs*s1 + e0;
        float n1 = fLs*s0 + fLc*s1 + e1;
        s0 = n0; s1 = n1;
        S[c*512 + 2*p] = s0; S[c*512 + 2*p + 1] = s1;
    }
}

// ---------------------------------------------------------------------------
// Kernel 6: out[t][e] = sum_k H[t][k]*CET[k][e] + D[e]*X[e][t]
// Fixup h_t = local_t + gamma^{i+1} R((i+1)theta) * S_c is FUSED into the
// A-tile load (TAB/S are L2-resident), so U never gets a fixup pass.
__global__ __launch_bounds__(256) void k_gemm_out(const float* __restrict__ Hbuf,
                                                  const float* __restrict__ CET,
                                                  const float* __restrict__ X,
                                                  const float* __restrict__ Dvec,
                                                  const float* __restrict__ S,
                                                  const float* __restrict__ TAB,
                                                  float* __restrict__ out) {
    __shared__ float As[16][132];   // padded rows (528B, 16B-aligned)
    __shared__ float Bs[16][64];
    const int tid = threadIdx.x;
    const int tx = tid & 15, ty = tid >> 4;
    const int t0 = blockIdx.y * 128, e0 = blockIdx.x * 64;
    float acc[8][4] = {};
    for (int k0 = 0; k0 < 512; k0 += 16) {
        #pragma unroll
        for (int r = 0; r < 2; ++r) {
            int f = tid + r*256;
            int mm = f >> 2, kk4 = f & 3;
            const int t = t0 + mm;
            const int c = t >> 4, i = t & 15;       // chunk, offset (CHUNK=16)
            const int p0 = (k0 + kk4*4) >> 1;        // first of 2 pairs
            float4 v = *reinterpret_cast<const float4*>(Hbuf + t*512 + k0 + kk4*4);
            float4 tb = *reinterpret_cast<const float4*>(TAB + (i*256 + p0)*2); // gc0 gs0 gc1 gs1
            float4 sv = *reinterpret_cast<const float4*>(S + c*512 + 2*p0);     // s00 s01 s10 s11
            v.x += tb.x*sv.x - tb.y*sv.y;
            v.y += tb.y*sv.x + tb.x*sv.y;
            v.z += tb.z*sv.z - tb.w*sv.w;
            v.w += tb.w*sv.z + tb.z*sv.w;
            As[kk4*4 + 0][mm] = v.x;    // transpose into LDS
            As[kk4*4 + 1][mm] = v.y;
            As[kk4*4 + 2][mm] = v.z;
            As[kk4*4 + 3][mm] = v.w;
        }
        {
            int kk = tid >> 4, ee4 = tid & 15;
            float4 v = *reinterpret_cast<const float4*>(CET + (k0 + kk)*512 + e0 + ee4*4);
            *reinterpret_cast<float4*>(&Bs[kk][ee4*4]) = v;
        }
        __syncthreads();
        #pragma unroll
        for (int kk = 0; kk < 16; ++kk) {
            float a[8], b[4];
            *reinterpret_cast<float4*>(a)     = *reinterpret_cast<const float4*>(&As[kk][ty*8]);
            *reinterpret_cast<float4*>(a + 4) = *reinterpret_cast<const float4*>(&As[kk][ty*8 + 4]);
            *reinterpret_cast<float4*>(b)     = *reinterpret_cast<const float4*>(&Bs[kk][tx*4]);
            #pragma unroll
            for (int ii = 0; ii < 8; ++ii)
                #pragma unroll
                for (int jj = 0; jj < 4; ++jj)
                    acc[ii][jj] = fmaf(a[ii], b[jj], acc[ii][jj]);
        }
        __syncthreads();
    }
    #pragma unroll
    for (int jj = 0; jj < 4; ++jj) {
        const int e = e0 + tx*4 + jj;
        const float dv = Dvec[e];
        #pragma unroll
        for (int ii = 0; ii < 8; ++ii) {
            const int t = t0 + ty*8 + ii;
            acc[ii][jj] += dv * X[e*4096 + t];
        }
    }
    #pragma unroll
    for (int ii = 0; ii < 8; ++ii) {
        float4 v = make_float4(acc[ii][0], acc[ii][1], acc[ii][2], acc[ii][3]);
        *reinterpret_cast<float4*>(out + (t0 + ty*8 + ii)*512 + e0 + tx*4) = v;
    }
}

// ---------------------------------------------------------------------------
extern "C" void kernel_launch(void* const* d_in, const int* in_sizes, int n_in,
                              void* d_out, int out_size, void* d_ws, size_t ws_size,
                              hipStream_t stream) {
    const float* X  = (const float*)d_in[0];  // (8,1,512,1,4096); batch 0 = first 2M floats
    const float* th = (const float*)d_in[1];  // theta_log (256)
    const float* P  = (const float*)d_in[2];  // (512,8)
    const float* Bm = (const float*)d_in[3];  // (512,512)
    const float* C  = (const float*)d_in[4];  // (512,512)
    const float* Dv = (const float*)d_in[5];  // (512)
    const float* gl = (const float*)d_in[6];  // gamma_log (64)
    float* ws  = (float*)d_ws;
    float* W1T = ws + 8192;
    float* CET = ws + 270336;
    float* U   = ws + 532480;
    float* E   = ws + 2629632;
    float* S   = ws + 2760704;
    float* TAB = ws + 2891776;
    float* out = (float*)d_out;

    k_setup<<<NHEADS, 64, 0, stream>>>(P, Bm, th, gl, ws);
    k_proj<<<2048, 256, 0, stream>>>(Bm, C, ws, W1T, CET);
    k_gemm_u<<<dim3(8, 32), 256, 0, stream>>>(X, W1T, U);
    k_scan_local<<<NCHUNK, 256, 0, stream>>>(U, E, ws);
    k_carry<<<1, 256, 0, stream>>>(E, S, TAB, th, gl);
    k_gemm_out<<<dim3(8, 32), 256, 0, stream>>>(U, CET, X, Dv, S, TAB, out);
}

// Round 3
// 163.287 us; speedup vs baseline: 1.4467x; 1.4467x over previous
//
#include <hip/hip_runtime.h>
#include <math.h>

// Problem constants
#define NHEADS   64
#define TLEN     4096
#define CHUNK    16
#define NCHUNK   256  // TLEN / CHUNK

typedef unsigned short u16;
typedef unsigned int   u32;
typedef __attribute__((ext_vector_type(8))) short bf16x8;   // 8 bf16 in 4 VGPRs
typedef __attribute__((ext_vector_type(4))) float f32x4;

__device__ __forceinline__ u16 f2bf(float x) {               // RNE f32->bf16
    u32 u = __float_as_uint(x);
    u32 r = (u + 0x7FFFu + ((u >> 16) & 1u)) >> 16;
    return (u16)r;
}
__device__ __forceinline__ float bf2f(u16 h) { return __uint_as_float(((u32)h) << 16); }

// ws layout (BYTE offsets)
//  params f32 : 0        (Pm 4096 f, gamma @4096, theta @4160, norm @4416)
//  W1pk  u16  : 32768    512 rows x (512 hi + 512 lo)          (1 MB)
//  CEpk  u16  : 1081344  512 rows x (512 hi + 512 lo)          (1 MB)
//  XTpk  u16  : 2129920  4096 rows x (512 hi + 512 lo)         (8 MB)
//  U     f32  : 10518528 4096 x 512 (becomes Hpk u16 in place) (8 MB)
//  E     f32  : 18907136 256 x 512                             (512 KB)
//  S     f32  : 19431424 256 x 512                             (512 KB)
//  TAB   f32  : 19955712 16 x 256 x 2                          (32 KB)
// total ~19.1 MB

// ---------------------------------------------------------------------------
// Kernel 1: per-head params + expm(P - P^T), fp64 scaling-and-squaring Taylor.
__global__ void k_setup(const float* __restrict__ P,
                        const float* __restrict__ Bmat,
                        const float* __restrict__ theta_log,
                        const float* __restrict__ gamma_log,
                        float* __restrict__ ws) {
    __shared__ double As[8][8];
    __shared__ double Rs[8][8];
    __shared__ double red[64];
    __shared__ int sh_s;
    const int h = blockIdx.x;
    const int tid = threadIdx.x;
    const int i = tid >> 3, j = tid & 7;

    As[i][j] = (double)P[(h*8 + i)*8 + j] - (double)P[(h*8 + j)*8 + i];

    const float* Bh = Bmat + h*8*512;
    double ss = 0.0;
    for (int q = 0; q < 64; ++q) { float v = Bh[q*64 + tid]; ss += (double)v * (double)v; }
    red[tid] = ss;
    __syncthreads();

    if (tid == 0) {
        double nrm = 0.0;
        for (int r = 0; r < 8; ++r) {
            double rs = 0.0;
            for (int c = 0; c < 8; ++c) rs += fabs(As[r][c]);
            nrm = fmax(nrm, rs);
        }
        int s = 0;
        while (nrm > 0.25 && s < 40) { nrm *= 0.5; ++s; }
        sh_s = s;
        double tr = 0.0;
        for (int q = 0; q < 64; ++q) tr += red[q];
        double ed = exp((double)gamma_log[h]);
        double g  = exp(-ed);
        ws[4096 + h] = (float)g;
        ws[4416 + h] = (float)sqrt((1.0 - g*g) / tr);
    }
    if (tid < 4) ws[4160 + h*4 + tid] = expf(theta_log[h*4 + tid]);
    __syncthreads();

    const double sc = ldexp(1.0, -sh_s);
    As[i][j] *= sc;
    const int NT = 13;
    Rs[i][j] = (i == j ? 1.0 : 0.0) + As[i][j] / (double)NT;
    __syncthreads();
    for (int k = NT - 1; k >= 1; --k) {
        double t = 0.0;
        #pragma unroll
        for (int m = 0; m < 8; ++m) t += As[i][m] * Rs[m][j];
        __syncthreads();
        Rs[i][j] = (i == j ? 1.0 : 0.0) + t / (double)k;
        __syncthreads();
    }
    for (int q = 0; q < sh_s; ++q) {
        double t = 0.0;
        #pragma unroll
        for (int m = 0; m < 8; ++m) t += Rs[i][m] * Rs[m][j];
        __syncthreads();
        Rs[i][j] = t;
        __syncthreads();
    }
    ws[h*64 + i*8 + j] = (float)Rs[i][j];
}

// ---------------------------------------------------------------------------
// Kernel 2: fold Pm into B (-> W1pk[k][d]) and C (-> CEpk[e][k]), pack hi/lo bf16.
__global__ void k_proj(const float* __restrict__ Bmat,
                       const float* __restrict__ C,
                       const float* __restrict__ ws_ro,
                       u16* __restrict__ W1pk,
                       u16* __restrict__ CEpk) {
    const int gid = blockIdx.x * 256 + threadIdx.x;
    if (gid < 512*512) {
        const int k = gid >> 9, d = gid & 511;
        const int h = k >> 3, N = k & 7;
        const float* Pm = ws_ro + h*64 + N*8;
        const float nrm = ws_ro[4416 + h];
        float acc = 0.f;
        #pragma unroll
        for (int n = 0; n < 8; ++n) acc += Pm[n] * Bmat[(h*8 + n)*512 + d];
        acc *= nrm;
        u16 hi = f2bf(acc), lo = f2bf(acc - bf2f(hi));
        W1pk[k*1024 + d] = hi;
        W1pk[k*1024 + 512 + d] = lo;
    } else {
        const int g2 = gid - 512*512;
        const int e = g2 >> 9, k = g2 & 511;
        const int h = k >> 3, N = k & 7;
        const float* Pm = ws_ro + h*64 + N*8;
        float acc = 0.f;
        #pragma unroll
        for (int n = 0; n < 8; ++n) acc += Pm[n] * C[e*512 + h*8 + n];
        u16 hi = f2bf(acc), lo = f2bf(acc - bf2f(hi));
        CEpk[e*1024 + k] = hi;
        CEpk[e*1024 + 512 + k] = lo;
    }
}

// ---------------------------------------------------------------------------
// Kernel 3: transpose X[d][t] -> XTpk[t]{hi[512],lo[512]} bf16 packed rows.
__global__ void k_xt(const float* __restrict__ X, u16* __restrict__ XT) {
    __shared__ float Xs[64][65];
    const int tid = threadIdx.x;
    const int t0 = blockIdx.x * 64, d0 = blockIdx.y * 64;
    {
        const int dr = tid >> 4, tc = (tid & 15) * 4;
        #pragma unroll
        for (int it = 0; it < 4; ++it) {
            const int dd = it*16 + dr;
            float4 v = *reinterpret_cast<const float4*>(X + (size_t)(d0 + dd)*4096 + t0 + tc);
            Xs[dd][tc] = v.x; Xs[dd][tc+1] = v.y; Xs[dd][tc+2] = v.z; Xs[dd][tc+3] = v.w;
        }
    }
    __syncthreads();
    const int tr = tid >> 2, ds = (tid & 3) * 16;
    u32 hb[8], lb[8];
    #pragma unroll
    for (int j = 0; j < 16; j += 2) {
        float a = Xs[ds + j][tr], b = Xs[ds + j + 1][tr];
        u16 ha = f2bf(a), la = f2bf(a - bf2f(ha));
        u16 hbb = f2bf(b), lbb = f2bf(b - bf2f(hbb));
        hb[j >> 1] = (u32)ha | ((u32)hbb << 16);
        lb[j >> 1] = (u32)la | ((u32)lbb << 16);
    }
    u16* orow = XT + (size_t)(t0 + tr)*1024 + d0 + ds;
    uint4 h0; h0.x = hb[0]; h0.y = hb[1]; h0.z = hb[2]; h0.w = hb[3];
    uint4 h1; h1.x = hb[4]; h1.y = hb[5]; h1.z = hb[6]; h1.w = hb[7];
    uint4 l0; l0.x = lb[0]; l0.y = lb[1]; l0.z = lb[2]; l0.w = lb[3];
    uint4 l1; l1.x = lb[4]; l1.y = lb[5]; l1.z = lb[6]; l1.w = lb[7];
    *reinterpret_cast<uint4*>(orow)       = h0;
    *reinterpret_cast<uint4*>(orow + 8)   = h1;
    *reinterpret_cast<uint4*>(orow + 512) = l0;
    *reinterpret_cast<uint4*>(orow + 520) = l1;
}

// ---------------------------------------------------------------------------
// Kernel 4/8: split-bf16 MFMA GEMM.  Cout[m][n] = sum_k A[m][k]*B[n][k].
// A_pk/B_pk rows: 1024 u16 = hi[512] then lo[512].  64x64 tile, 4 waves 2x2,
// BK=64 (2 MFMA k-blocks per stage).  EPI=1 adds D*x epilogue (x from XTpk).
#define MFMA_BF16(A_, B_, C_) __builtin_amdgcn_mfma_f32_16x16x32_bf16(A_, B_, C_, 0, 0, 0)
template<int EPI>
__global__ __launch_bounds__(256) void k_gemm(const u16* __restrict__ Apk,
                                              const u16* __restrict__ Bpk,
                                              float* __restrict__ Cout,
                                              const u16* __restrict__ XT,
                                              const float* __restrict__ Dvec) {
    __shared__ u16 Ah[64*72], Al[64*72], Bh[64*72], Bl[64*72];  // 144B rows: even banks
    const int tid = threadIdx.x;
    // XCD-chunked swizzle: consecutive original m-panels land on one XCD's L2.
    const int bid = blockIdx.x;
    const int tile = (bid & 7) * 64 + (bid >> 3);
    const int mt = tile >> 3, nt = tile & 7;
    const int m0 = mt * 64, n0 = nt * 64;
    const int lane = tid & 63, wid = tid >> 6;
    const int wm = wid >> 1, wn = wid & 1;
    const int lr = lane & 15, lc = lane >> 4;
    const int sr = tid >> 2, ss = (tid & 3) * 16;   // staging: row 0..63, 16-u16 seg

    f32x4 acc00 = {0.f,0.f,0.f,0.f}, acc01 = acc00, acc10 = acc00, acc11 = acc00;

    const u16* Arow = Apk + (size_t)(m0 + sr)*1024 + ss;
    const u16* Brow = Bpk + (size_t)(n0 + sr)*1024 + ss;

    for (int k0 = 0; k0 < 512; k0 += 64) {
        float4 vah0 = *reinterpret_cast<const float4*>(Arow + k0);
        float4 vah1 = *reinterpret_cast<const float4*>(Arow + k0 + 8);
        float4 val0 = *reinterpret_cast<const float4*>(Arow + 512 + k0);
        float4 val1 = *reinterpret_cast<const float4*>(Arow + 512 + k0 + 8);
        float4 vbh0 = *reinterpret_cast<const float4*>(Brow + k0);
        float4 vbh1 = *reinterpret_cast<const float4*>(Brow + k0 + 8);
        float4 vbl0 = *reinterpret_cast<const float4*>(Brow + 512 + k0);
        float4 vbl1 = *reinterpret_cast<const float4*>(Brow + 512 + k0 + 8);
        *reinterpret_cast<float4*>(&Ah[sr*72 + ss])     = vah0;
        *reinterpret_cast<float4*>(&Ah[sr*72 + ss + 8]) = vah1;
        *reinterpret_cast<float4*>(&Al[sr*72 + ss])     = val0;
        *reinterpret_cast<float4*>(&Al[sr*72 + ss + 8]) = val1;
        *reinterpret_cast<float4*>(&Bh[sr*72 + ss])     = vbh0;
        *reinterpret_cast<float4*>(&Bh[sr*72 + ss + 8]) = vbh1;
        *reinterpret_cast<float4*>(&Bl[sr*72 + ss])     = vbl0;
        *reinterpret_cast<float4*>(&Bl[sr*72 + ss + 8]) = vbl1;
        __syncthreads();
        #pragma unroll
        for (int kk = 0; kk < 2; ++kk) {
            const int ko = kk*32 + lc*8;
            const int ra0 = (wm*32 + lr)*72 + ko,  ra1 = ra0 + 16*72;
            const int rb0 = (wn*32 + lr)*72 + ko,  rb1 = rb0 + 16*72;
            bf16x8 fah0 = *reinterpret_cast<const bf16x8*>(&Ah[ra0]);
            bf16x8 fah1 = *reinterpret_cast<const bf16x8*>(&Ah[ra1]);
            bf16x8 fal0 = *reinterpret_cast<const bf16x8*>(&Al[ra0]);
            bf16x8 fal1 = *reinterpret_cast<const bf16x8*>(&Al[ra1]);
            bf16x8 fbh0 = *reinterpret_cast<const bf16x8*>(&Bh[rb0]);
            bf16x8 fbh1 = *reinterpret_cast<const bf16x8*>(&Bh[rb1]);
            bf16x8 fbl0 = *reinterpret_cast<const bf16x8*>(&Bl[rb0]);
            bf16x8 fbl1 = *reinterpret_cast<const bf16x8*>(&Bl[rb1]);
            acc00 = MFMA_BF16(fah0, fbl0, acc00);
            acc00 = MFMA_BF16(fal0, fbh0, acc00);
            acc00 = MFMA_BF16(fah0, fbh0, acc00);
            acc01 = MFMA_BF16(fah0, fbl1, acc01);
            acc01 = MFMA_BF16(fal0, fbh1, acc01);
            acc01 = MFMA_BF16(fah0, fbh1, acc01);
            acc10 = MFMA_BF16(fah1, fbl0, acc10);
            acc10 = MFMA_BF16(fal1, fbh0, acc10);
            acc10 = MFMA_BF16(fah1, fbh0, acc10);
            acc11 = MFMA_BF16(fah1, fbl1, acc11);
            acc11 = MFMA_BF16(fal1, fbh1, acc11);
            acc11 = MFMA_BF16(fah1, fbh1, acc11);
        }
        __syncthreads();
    }

    #pragma unroll
    for (int im = 0; im < 2; ++im) {
        #pragma unroll
        for (int in = 0; in < 2; ++in) {
            f32x4 v = (im == 0) ? (in == 0 ? acc00 : acc01)
                                : (in == 0 ? acc10 : acc11);
            const int row0 = m0 + wm*32 + im*16 + lc*4;
            const int col  = n0 + wn*32 + in*16 + lr;
            if (EPI == 0) {
                #pragma unroll
                for (int rg = 0; rg < 4; ++rg)
                    Cout[(size_t)(row0 + rg)*512 + col] = v[rg];
            } else {
                const float dv = Dvec[col];
                #pragma unroll
                for (int rg = 0; rg < 4; ++rg) {
                    const int t = row0 + rg;
                    float xv = bf2f(XT[(size_t)t*1024 + col]) + bf2f(XT[(size_t)t*1024 + 512 + col]);
                    Cout[(size_t)t*512 + col] = v[rg] + dv*xv;
                }
            }
        }
    }
}

// ---------------------------------------------------------------------------
// Kernel 5: per-chunk local scan, in place; all CHUNK rows prefetched to regs.
__global__ void k_scan(float* __restrict__ U, float* __restrict__ E,
                       const float* __restrict__ ws_ro) {
    const int c = blockIdx.x;
    const int p = threadIdx.x;
    const float th = ws_ro[4160 + p];
    const float g  = ws_ro[4096 + (p >> 2)];
    const float cs = cosf(th), sn = sinf(th);
    float* base = U + (size_t)c*CHUNK*512 + 2*p;
    float2 u[CHUNK];
    #pragma unroll
    for (int i = 0; i < CHUNK; ++i) u[i] = *reinterpret_cast<float2*>(base + (size_t)i*512);
    float h0 = 0.f, h1 = 0.f;
    #pragma unroll
    for (int i = 0; i < CHUNK; ++i) {
        float n0 = g*(cs*h0 - sn*h1) + u[i].x;
        float n1 = g*(sn*h0 + cs*h1) + u[i].y;
        h0 = n0; h1 = n1;
        u[i] = make_float2(n0, n1);
    }
    #pragma unroll
    for (int i = 0; i < CHUNK; ++i) *reinterpret_cast<float2*>(base + (size_t)i*512) = u[i];
    E[c*512 + 2*p]     = h0;
    E[c*512 + 2*p + 1] = h1;
}

// ---------------------------------------------------------------------------
// Kernel 6: TAB + sequential carry over chunk ends, double-buffered batches.
__global__ void k_carry(const float* __restrict__ E, float* __restrict__ S,
                        float* __restrict__ TAB,
                        const float* __restrict__ theta_log,
                        const float* __restrict__ gamma_log) {
    const int p = threadIdx.x;
    const double th = exp((double)theta_log[p]);
    const double ed = exp((double)gamma_log[p >> 2]);
    const double g  = exp(-ed);
    const double cd = cos(th), sd = sin(th);
    double gc = g*cd, gs = g*sd;
    for (int i = 0; i < CHUNK; ++i) {
        if (i) {
            double t0 = g*(cd*gc - sd*gs);
            double t1 = g*(sd*gc + cd*gs);
            gc = t0; gs = t1;
        }
        TAB[(i*256 + p)*2 + 0] = (float)gc;
        TAB[(i*256 + p)*2 + 1] = (float)gs;
    }
    const float fLc = (float)gc, fLs = (float)gs;
    float s0 = 0.f, s1 = 0.f;
    S[2*p] = 0.f; S[2*p + 1] = 0.f;
    const float* Ep = E + 2*p;
    float* Sp = S + 2*p;
    float2 bA[16], bB[16];
    #pragma unroll
    for (int j = 0; j < 16; ++j) bA[j] = *reinterpret_cast<const float2*>(Ep + (size_t)j*512);
    for (int bb = 0; bb < 8; ++bb) {
        const int b0 = 2*bb, b1 = 2*bb + 1;
        #pragma unroll
        for (int j = 0; j < 16; ++j)
            bB[j] = *reinterpret_cast<const float2*>(Ep + (size_t)(b1*16 + j)*512);
        #pragma unroll
        for (int j = 0; j < 16; ++j) {
            const int c = b0*16 + j + 1;
            float n0 = fLc*s0 - fLs*s1 + bA[j].x;
            float n1 = fLs*s0 + fLc*s1 + bA[j].y;
            s0 = n0; s1 = n1;
            *reinterpret_cast<float2*>(Sp + (size_t)c*512) = make_float2(s0, s1);
        }
        if (b1 + 1 < 16) {
            #pragma unroll
            for (int j = 0; j < 16; ++j)
                bA[j] = *reinterpret_cast<const float2*>(Ep + (size_t)((b1 + 1)*16 + j)*512);
        }
        #pragma unroll
        for (int j = 0; j < 16; ++j) {
            const int c = b1*16 + j + 1;
            float n0 = fLc*s0 - fLs*s1 + bB[j].x;
            float n1 = fLs*s0 + fLc*s1 + bB[j].y;
            s0 = n0; s1 = n1;
            if (c < NCHUNK)
                *reinterpret_cast<float2*>(Sp + (size_t)c*512) = make_float2(s0, s1);
        }
    }
}

// ---------------------------------------------------------------------------
// Kernel 7: fixup h_t += gamma^{i+1} R((i+1)theta) * S_c, then pack U row ->
// {hi[512], lo[512]} bf16 IN PLACE (row-exclusive per wave: no races).
__global__ void k_fixpack(float* __restrict__ U, const float* __restrict__ S,
                          const float* __restrict__ TAB) {
    const int t = blockIdx.x*4 + (threadIdx.x >> 6);
    const int l = threadIdx.x & 63;
    float* row = U + (size_t)t*512;
    float4 v0 = *reinterpret_cast<float4*>(row + l*4);          // k = 4l..4l+3
    float4 v1 = *reinterpret_cast<float4*>(row + 256 + l*4);    // k = 256+4l..
    const int c = t >> 4, i = t & 15;
    float4 tb0 = *reinterpret_cast<const float4*>(TAB + ((size_t)i*256 + 2*l)*2);
    float4 sv0 = *reinterpret_cast<const float4*>(S + (size_t)c*512 + 4*l);
    float4 tb1 = *reinterpret_cast<const float4*>(TAB + ((size_t)i*256 + 128 + 2*l)*2);
    float4 sv1 = *reinterpret_cast<const float4*>(S + (size_t)c*512 + 256 + 4*l);
    v0.x += tb0.x*sv0.x - tb0.y*sv0.y;  v0.y += tb0.y*sv0.x + tb0.x*sv0.y;
    v0.z += tb0.z*sv0.z - tb0.w*sv0.w;  v0.w += tb0.w*sv0.z + tb0.z*sv0.w;
    v1.x += tb1.x*sv1.x - tb1.y*sv1.y;  v1.y += tb1.y*sv1.x + tb1.x*sv1.y;
    v1.z += tb1.z*sv1.z - tb1.w*sv1.w;  v1.w += tb1.w*sv1.z + tb1.z*sv1.w;
    u16 h0x = f2bf(v0.x), h0y = f2bf(v0.y), h0z = f2bf(v0.z), h0w = f2bf(v0.w);
    u16 h1x = f2bf(v1.x), h1y = f2bf(v1.y), h1z = f2bf(v1.z), h1w = f2bf(v1.w);
    u16 l0x = f2bf(v0.x - bf2f(h0x)), l0y = f2bf(v0.y - bf2f(h0y));
    u16 l0z = f2bf(v0.z - bf2f(h0z)), l0w = f2bf(v0.w - bf2f(h0w));
    u16 l1x = f2bf(v1.x - bf2f(h1x)), l1y = f2bf(v1.y - bf2f(h1y));
    u16 l1z = f2bf(v1.z - bf2f(h1z)), l1w = f2bf(v1.w - bf2f(h1w));
    u16* ur = reinterpret_cast<u16*>(row);
    uint2 w0; w0.x = (u32)h0x | ((u32)h0y << 16); w0.y = (u32)h0z | ((u32)h0w << 16);
    uint2 w1; w1.x = (u32)h1x | ((u32)h1y << 16); w1.y = (u32)h1z | ((u32)h1w << 16);
    uint2 w2; w2.x = (u32)l0x | ((u32)l0y << 16); w2.y = (u32)l0z | ((u32)l0w << 16);
    uint2 w3; w3.x = (u32)l1x | ((u32)l1y << 16); w3.y = (u32)l1z | ((u32)l1w << 16);
    *reinterpret_cast<uint2*>(ur + 4*l)       = w0;   // hi, k<256
    *reinterpret_cast<uint2*>(ur + 256 + 4*l) = w1;   // hi, k>=256
    *reinterpret_cast<uint2*>(ur + 512 + 4*l) = w2;   // lo, k<256
    *reinterpret_cast<uint2*>(ur + 768 + 4*l) = w3;   // lo, k>=256
}

// ---------------------------------------------------------------------------
extern "C" void kernel_launch(void* const* d_in, const int* in_sizes, int n_in,
                              void* d_out, int out_size, void* d_ws, size_t ws_size,
                              hipStream_t stream) {
    const float* X  = (const float*)d_in[0];  // (8,1,512,1,4096); batch 0 = first 2M floats
    const float* th = (const float*)d_in[1];
    const float* P  = (const float*)d_in[2];
    const float* Bm = (const float*)d_in[3];
    const float* C  = (const float*)d_in[4];
    const float* Dv = (const float*)d_in[5];
    const float* gl = (const float*)d_in[6];
    char* wsb = (char*)d_ws;
    float* ws   = (float*)wsb;
    u16*   W1pk = (u16*)(wsb + 32768);
    u16*   CEpk = (u16*)(wsb + 1081344);
    u16*   XTpk = (u16*)(wsb + 2129920);
    float* U    = (float*)(wsb + 10518528);
    float* E    = (float*)(wsb + 18907136);
    float* S    = (float*)(wsb + 19431424);
    float* TAB  = (float*)(wsb + 19955712);
    float* out  = (float*)d_out;

    k_setup<<<NHEADS, 64, 0, stream>>>(P, Bm, th, gl, ws);
    k_proj<<<2048, 256, 0, stream>>>(Bm, C, ws, W1pk, CEpk);
    k_xt<<<dim3(64, 8), 256, 0, stream>>>(X, XTpk);
    k_gemm<0><<<512, 256, 0, stream>>>(XTpk, W1pk, U, XTpk, Dv);
    k_scan<<<NCHUNK, 256, 0, stream>>>(U, E, ws);
    k_carry<<<1, 256, 0, stream>>>(E, S, TAB, th, gl);
    k_fixpack<<<1024, 256, 0, stream>>>(U, S, TAB);
    k_gemm<1><<<512, 256, 0, stream>>>((const u16*)U, CEpk, out, XTpk, Dv);
}

// Round 4
// 161.006 us; speedup vs baseline: 1.4672x; 1.0142x over previous
//
#include <hip/hip_runtime.h>
#include <math.h>

// Problem constants
#define NHEADS   64
#define TLEN     4096
#define CHUNK    16
#define NCHUNK   256  // TLEN / CHUNK

typedef unsigned short u16;
typedef unsigned int   u32;
typedef __attribute__((ext_vector_type(8))) short bf16x8;   // 8 bf16 in 4 VGPRs
typedef __attribute__((ext_vector_type(4))) float f32x4;

__device__ __forceinline__ u16 f2bf(float x) {               // RNE f32->bf16
    u32 u = __float_as_uint(x);
    u32 r = (u + 0x7FFFu + ((u >> 16) & 1u)) >> 16;
    return (u16)r;
}
__device__ __forceinline__ float bf2f(u16 h) { return __uint_as_float(((u32)h) << 16); }

// ws layout (BYTE offsets)
//  params f32 : 0        (Pm 4096 f, gamma @4096, theta @4160, norm @4416)
//  W1pk  u16  : 32768    512 rows x (512 hi + 512 lo)          (1 MB)
//  CEpk  u16  : 1081344  512 rows x (512 hi + 512 lo)          (1 MB)
//  XTpk  u16  : 2129920  4096 rows x (512 hi + 512 lo)         (8 MB)
//  U     f32  : 10518528 4096 x 512 (scanned local states)     (8 MB)
//  E     f32  : 18907136 256 x 512                             (512 KB)
//  S     f32  : 19431424 256 x 512                             (512 KB)
//  TAB   f32  : 19955712 16 x 256 x 2                          (32 KB)

// ---------------------------------------------------------------------------
// Kernel 1: per-head params + expm(P - P^T), fp64 scaling-and-squaring Taylor.
__global__ void k_setup(const float* __restrict__ P,
                        const float* __restrict__ Bmat,
                        const float* __restrict__ theta_log,
                        const float* __restrict__ gamma_log,
                        float* __restrict__ ws) {
    __shared__ double As[8][8];
    __shared__ double Rs[8][8];
    __shared__ double red[64];
    __shared__ int sh_s;
    const int h = blockIdx.x;
    const int tid = threadIdx.x;
    const int i = tid >> 3, j = tid & 7;

    As[i][j] = (double)P[(h*8 + i)*8 + j] - (double)P[(h*8 + j)*8 + i];

    const float* Bh = Bmat + h*8*512;
    double ss = 0.0;
    for (int q = 0; q < 64; ++q) { float v = Bh[q*64 + tid]; ss += (double)v * (double)v; }
    red[tid] = ss;
    __syncthreads();

    if (tid == 0) {
        double nrm = 0.0;
        for (int r = 0; r < 8; ++r) {
            double rs = 0.0;
            for (int c = 0; c < 8; ++c) rs += fabs(As[r][c]);
            nrm = fmax(nrm, rs);
        }
        int s = 0;
        while (nrm > 0.25 && s < 40) { nrm *= 0.5; ++s; }
        sh_s = s;
        double tr = 0.0;
        for (int q = 0; q < 64; ++q) tr += red[q];
        double ed = exp((double)gamma_log[h]);
        double g  = exp(-ed);
        ws[4096 + h] = (float)g;
        ws[4416 + h] = (float)sqrt((1.0 - g*g) / tr);
    }
    if (tid < 4) ws[4160 + h*4 + tid] = expf(theta_log[h*4 + tid]);
    __syncthreads();

    const double sc = ldexp(1.0, -sh_s);
    As[i][j] *= sc;
    const int NT = 13;
    Rs[i][j] = (i == j ? 1.0 : 0.0) + As[i][j] / (double)NT;
    __syncthreads();
    for (int k = NT - 1; k >= 1; --k) {
        double t = 0.0;
        #pragma unroll
        for (int m = 0; m < 8; ++m) t += As[i][m] * Rs[m][j];
        __syncthreads();
        Rs[i][j] = (i == j ? 1.0 : 0.0) + t / (double)k;
        __syncthreads();
    }
    for (int q = 0; q < sh_s; ++q) {
        double t = 0.0;
        #pragma unroll
        for (int m = 0; m < 8; ++m) t += Rs[i][m] * Rs[m][j];
        __syncthreads();
        Rs[i][j] = t;
        __syncthreads();
    }
    ws[h*64 + i*8 + j] = (float)Rs[i][j];
}

// ---------------------------------------------------------------------------
// Kernel 2: fold Pm into B (-> W1pk[k][d]) and C (-> CEpk[e][k]), pack hi/lo bf16.
__global__ void k_proj(const float* __restrict__ Bmat,
                       const float* __restrict__ C,
                       const float* __restrict__ ws_ro,
                       u16* __restrict__ W1pk,
                       u16* __restrict__ CEpk) {
    const int gid = blockIdx.x * 256 + threadIdx.x;
    if (gid < 512*512) {
        const int k = gid >> 9, d = gid & 511;
        const int h = k >> 3, N = k & 7;
        const float* Pm = ws_ro + h*64 + N*8;
        const float nrm = ws_ro[4416 + h];
        float acc = 0.f;
        #pragma unroll
        for (int n = 0; n < 8; ++n) acc += Pm[n] * Bmat[(h*8 + n)*512 + d];
        acc *= nrm;
        u16 hi = f2bf(acc), lo = f2bf(acc - bf2f(hi));
        W1pk[k*1024 + d] = hi;
        W1pk[k*1024 + 512 + d] = lo;
    } else {
        const int g2 = gid - 512*512;
        const int e = g2 >> 9, k = g2 & 511;
        const int h = k >> 3, N = k & 7;
        const float* Pm = ws_ro + h*64 + N*8;
        float acc = 0.f;
        #pragma unroll
        for (int n = 0; n < 8; ++n) acc += Pm[n] * C[e*512 + h*8 + n];
        u16 hi = f2bf(acc), lo = f2bf(acc - bf2f(hi));
        CEpk[e*1024 + k] = hi;
        CEpk[e*1024 + 512 + k] = lo;
    }
}

// ---------------------------------------------------------------------------
// Kernel 3: transpose X[d][t] -> XTpk[t]{hi[512],lo[512]} bf16 packed rows.
__global__ void k_xt(const float* __restrict__ X, u16* __restrict__ XT) {
    __shared__ float Xs[64][65];
    const int tid = threadIdx.x;
    const int t0 = blockIdx.x * 64, d0 = blockIdx.y * 64;
    {
        const int dr = tid >> 4, tc = (tid & 15) * 4;
        #pragma unroll
        for (int it = 0; it < 4; ++it) {
            const int dd = it*16 + dr;
            float4 v = *reinterpret_cast<const float4*>(X + (size_t)(d0 + dd)*4096 + t0 + tc);
            Xs[dd][tc] = v.x; Xs[dd][tc+1] = v.y; Xs[dd][tc+2] = v.z; Xs[dd][tc+3] = v.w;
        }
    }
    __syncthreads();
    const int tr = tid >> 2, ds = (tid & 3) * 16;
    u32 hb[8], lb[8];
    #pragma unroll
    for (int j = 0; j < 16; j += 2) {
        float a = Xs[ds + j][tr], b = Xs[ds + j + 1][tr];
        u16 ha = f2bf(a), la = f2bf(a - bf2f(ha));
        u16 hbb = f2bf(b), lbb = f2bf(b - bf2f(hbb));
        hb[j >> 1] = (u32)ha | ((u32)hbb << 16);
        lb[j >> 1] = (u32)la | ((u32)lbb << 16);
    }
    u16* orow = XT + (size_t)(t0 + tr)*1024 + d0 + ds;
    uint4 h0; h0.x = hb[0]; h0.y = hb[1]; h0.z = hb[2]; h0.w = hb[3];
    uint4 h1; h1.x = hb[4]; h1.y = hb[5]; h1.z = hb[6]; h1.w = hb[7];
    uint4 l0; l0.x = lb[0]; l0.y = lb[1]; l0.z = lb[2]; l0.w = lb[3];
    uint4 l1; l1.x = lb[4]; l1.y = lb[5]; l1.z = lb[6]; l1.w = lb[7];
    *reinterpret_cast<uint4*>(orow)       = h0;
    *reinterpret_cast<uint4*>(orow + 8)   = h1;
    *reinterpret_cast<uint4*>(orow + 512) = l0;
    *reinterpret_cast<uint4*>(orow + 520) = l1;
}

// ---------------------------------------------------------------------------
// Kernel 4/6: split-bf16 MFMA GEMM, 64x64 tile, 4 waves 2x2, BK=64.
// MODE 0 (U-proj): A = XTpk packed rows; epilogue = in-LDS local scan of the
//   4 chunks this tile spans, writes scanned U (coalesced) + chunk-end E.
// MODE 1 (output): A = U f32 rows with carry fixup applied during staging
//   (hi/lo split in-register), epilogue = D*x added, writes out.
#define MFMA_BF16(A_, B_, C_) __builtin_amdgcn_mfma_f32_16x16x32_bf16(A_, B_, C_, 0, 0, 0)
template<int MODE>
__global__ __launch_bounds__(256) void k_gemm(const u16* __restrict__ Apk,
                                              const float* __restrict__ Af,
                                              const u16* __restrict__ Bpk,
                                              float* __restrict__ Cout,
                                              const u16* __restrict__ XT,
                                              const float* __restrict__ Dvec,
                                              const float* __restrict__ wsro,
                                              float* __restrict__ E,
                                              const float* __restrict__ S,
                                              const float* __restrict__ TAB) {
    __shared__ char smem[36864];
    u16* Ah = (u16*)smem;          // 64 rows x 72 u16
    u16* Al = Ah + 4608;
    u16* Bh = Al + 4608;
    u16* Bl = Bh + 4608;
    float* Ut = (float*)smem;      // MODE0 epilogue: 64 x 72 f32 == Ah+Al区 (18432 B)

    const int tid = threadIdx.x;
    const int bid = blockIdx.x;
    const int tile = (bid & 7) * 64 + (bid >> 3);   // XCD-chunked swizzle
    const int mt = tile >> 3, nt = tile & 7;
    const int m0 = mt * 64, n0 = nt * 64;
    const int lane = tid & 63, wid = tid >> 6;
    const int wm = wid >> 1, wn = wid & 1;
    const int lr = lane & 15, lc = lane >> 4;
    const int sr = tid >> 2, ss = (tid & 3) * 16;   // staging: row, 16-elem seg

    f32x4 acc00 = {0.f,0.f,0.f,0.f}, acc01 = acc00, acc10 = acc00, acc11 = acc00;

    const int tA = m0 + sr;                 // staging row (t index)
    const int cA = tA >> 4, iA = tA & 15;   // chunk, offset (MODE1 fix)
    const u16* Brow = Bpk + (size_t)(n0 + sr)*1024 + ss;
    const u16* Arow = (MODE == 0) ? (Apk + (size_t)tA*1024 + ss) : (const u16*)0;
    const float* Urow = (MODE == 1) ? (Af + (size_t)tA*512 + ss) : (const float*)0;

    for (int k0 = 0; k0 < 512; k0 += 64) {
        float4 vbh0 = *reinterpret_cast<const float4*>(Brow + k0);
        float4 vbh1 = *reinterpret_cast<const float4*>(Brow + k0 + 8);
        float4 vbl0 = *reinterpret_cast<const float4*>(Brow + 512 + k0);
        float4 vbl1 = *reinterpret_cast<const float4*>(Brow + 512 + k0 + 8);
        if constexpr (MODE == 0) {
            float4 vah0 = *reinterpret_cast<const float4*>(Arow + k0);
            float4 vah1 = *reinterpret_cast<const float4*>(Arow + k0 + 8);
            float4 val0 = *reinterpret_cast<const float4*>(Arow + 512 + k0);
            float4 val1 = *reinterpret_cast<const float4*>(Arow + 512 + k0 + 8);
            *reinterpret_cast<float4*>(&Ah[sr*72 + ss])     = vah0;
            *reinterpret_cast<float4*>(&Ah[sr*72 + ss + 8]) = vah1;
            *reinterpret_cast<float4*>(&Al[sr*72 + ss])     = val0;
            *reinterpret_cast<float4*>(&Al[sr*72 + ss + 8]) = val1;
        } else {
            // load 16 f32 of U, apply carry fixup, split hi/lo into LDS
            const int p0 = (k0 + ss) >> 1;
            #pragma unroll
            for (int j = 0; j < 4; ++j) {
                float4 u = *reinterpret_cast<const float4*>(Urow + k0 + 4*j);
                float4 tb = *reinterpret_cast<const float4*>(TAB + ((size_t)iA*256 + p0 + 2*j)*2);
                float4 sv = *reinterpret_cast<const float4*>(S + (size_t)cA*512 + 2*p0 + 4*j);
                u.x += tb.x*sv.x - tb.y*sv.y;
                u.y += tb.y*sv.x + tb.x*sv.y;
                u.z += tb.z*sv.z - tb.w*sv.w;
                u.w += tb.w*sv.z + tb.z*sv.w;
                u16 hx = f2bf(u.x), hy = f2bf(u.y), hz = f2bf(u.z), hw = f2bf(u.w);
                u16 lx = f2bf(u.x - bf2f(hx)), ly = f2bf(u.y - bf2f(hy));
                u16 lz = f2bf(u.z - bf2f(hz)), lw = f2bf(u.w - bf2f(hw));
                uint2 wh; wh.x = (u32)hx | ((u32)hy << 16); wh.y = (u32)hz | ((u32)hw << 16);
                uint2 wl; wl.x = (u32)lx | ((u32)ly << 16); wl.y = (u32)lz | ((u32)lw << 16);
                *reinterpret_cast<uint2*>(&Ah[sr*72 + ss + 4*j]) = wh;
                *reinterpret_cast<uint2*>(&Al[sr*72 + ss + 4*j]) = wl;
            }
        }
        *reinterpret_cast<float4*>(&Bh[sr*72 + ss])     = vbh0;
        *reinterpret_cast<float4*>(&Bh[sr*72 + ss + 8]) = vbh1;
        *reinterpret_cast<float4*>(&Bl[sr*72 + ss])     = vbl0;
        *reinterpret_cast<float4*>(&Bl[sr*72 + ss + 8]) = vbl1;
        __syncthreads();
        #pragma unroll
        for (int kk = 0; kk < 2; ++kk) {
            const int ko = kk*32 + lc*8;
            const int ra0 = (wm*32 + lr)*72 + ko,  ra1 = ra0 + 16*72;
            const int rb0 = (wn*32 + lr)*72 + ko,  rb1 = rb0 + 16*72;
            bf16x8 fah0 = *reinterpret_cast<const bf16x8*>(&Ah[ra0]);
            bf16x8 fah1 = *reinterpret_cast<const bf16x8*>(&Ah[ra1]);
            bf16x8 fal0 = *reinterpret_cast<const bf16x8*>(&Al[ra0]);
            bf16x8 fal1 = *reinterpret_cast<const bf16x8*>(&Al[ra1]);
            bf16x8 fbh0 = *reinterpret_cast<const bf16x8*>(&Bh[rb0]);
            bf16x8 fbh1 = *reinterpret_cast<const bf16x8*>(&Bh[rb1]);
            bf16x8 fbl0 = *reinterpret_cast<const bf16x8*>(&Bl[rb0]);
            bf16x8 fbl1 = *reinterpret_cast<const bf16x8*>(&Bl[rb1]);
            acc00 = MFMA_BF16(fah0, fbl0, acc00);
            acc00 = MFMA_BF16(fal0, fbh0, acc00);
            acc00 = MFMA_BF16(fah0, fbh0, acc00);
            acc01 = MFMA_BF16(fah0, fbl1, acc01);
            acc01 = MFMA_BF16(fal0, fbh1, acc01);
            acc01 = MFMA_BF16(fah0, fbh1, acc01);
            acc10 = MFMA_BF16(fah1, fbl0, acc10);
            acc10 = MFMA_BF16(fal1, fbh0, acc10);
            acc10 = MFMA_BF16(fah1, fbh0, acc10);
            acc11 = MFMA_BF16(fah1, fbl1, acc11);
            acc11 = MFMA_BF16(fal1, fbh1, acc11);
            acc11 = MFMA_BF16(fah1, fbh1, acc11);
        }
        __syncthreads();
    }

    if constexpr (MODE == 0) {
        // ---- fused local scan epilogue ----
        #pragma unroll
        for (int im = 0; im < 2; ++im) {
            #pragma unroll
            for (int in = 0; in < 2; ++in) {
                f32x4 v = (im == 0) ? (in == 0 ? acc00 : acc01)
                                    : (in == 0 ? acc10 : acc11);
                const int row0 = wm*32 + im*16 + lc*4;
                const int col  = wn*32 + in*16 + lr;
                #pragma unroll
                for (int rg = 0; rg < 4; ++rg)
                    Ut[(row0 + rg)*72 + col] = v[rg];
            }
        }
        __syncthreads();
        if (tid < 128) {
            const int cc = tid >> 5, pp = tid & 31;   // local chunk 0..3, local pair
            const int pg = nt*32 + pp;                // global pair
            const float th = wsro[4160 + pg];
            const float g  = wsro[4096 + (pg >> 2)];
            const float cs = cosf(th), sn = sinf(th);
            float h0 = 0.f, h1 = 0.f;
            float* col = Ut + (cc*16)*72 + 2*pp;
            #pragma unroll
            for (int i = 0; i < CHUNK; ++i) {
                float a = col[i*72], b = col[i*72 + 1];
                float n0v = g*(cs*h0 - sn*h1) + a;
                float n1v = g*(sn*h0 + cs*h1) + b;
                col[i*72] = n0v; col[i*72 + 1] = n1v;
                h0 = n0v; h1 = n1v;
            }
            E[(size_t)(mt*4 + cc)*512 + 2*pg]     = h0;
            E[(size_t)(mt*4 + cc)*512 + 2*pg + 1] = h1;
        }
        __syncthreads();
        const int row = tid >> 2, cseg = (tid & 3) * 16;
        #pragma unroll
        for (int j = 0; j < 4; ++j) {
            float4 v = *reinterpret_cast<const float4*>(&Ut[row*72 + cseg + 4*j]);
            *reinterpret_cast<float4*>(Cout + (size_t)(m0 + row)*512 + n0 + cseg + 4*j) = v;
        }
    } else {
        // ---- D*x epilogue ----
        #pragma unroll
        for (int im = 0; im < 2; ++im) {
            #pragma unroll
            for (int in = 0; in < 2; ++in) {
                f32x4 v = (im == 0) ? (in == 0 ? acc00 : acc01)
                                    : (in == 0 ? acc10 : acc11);
                const int row0 = m0 + wm*32 + im*16 + lc*4;
                const int col  = n0 + wn*32 + in*16 + lr;
                const float dv = Dvec[col];
                #pragma unroll
                for (int rg = 0; rg < 4; ++rg) {
                    const int t = row0 + rg;
                    float xv = bf2f(XT[(size_t)t*1024 + col]) + bf2f(XT[(size_t)t*1024 + 512 + col]);
                    Cout[(size_t)t*512 + col] = v[rg] + dv*xv;
                }
            }
        }
    }
}

// ---------------------------------------------------------------------------
// Kernel 5: TAB + sequential carry over chunk ends, double-buffered batches.
__global__ void k_carry(const float* __restrict__ E, float* __restrict__ S,
                        float* __restrict__ TAB,
                        const float* __restrict__ theta_log,
                        const float* __restrict__ gamma_log) {
    const int p = threadIdx.x;
    const double th = exp((double)theta_log[p]);
    const double ed = exp((double)gamma_log[p >> 2]);
    const double g  = exp(-ed);
    const double cd = cos(th), sd = sin(th);
    double gc = g*cd, gs = g*sd;
    for (int i = 0; i < CHUNK; ++i) {
        if (i) {
            double t0 = g*(cd*gc - sd*gs);
            double t1 = g*(sd*gc + cd*gs);
            gc = t0; gs = t1;
        }
        TAB[(i*256 + p)*2 + 0] = (float)gc;
        TAB[(i*256 + p)*2 + 1] = (float)gs;
    }
    const float fLc = (float)gc, fLs = (float)gs;
    float s0 = 0.f, s1 = 0.f;
    S[2*p] = 0.f; S[2*p + 1] = 0.f;
    const float* Ep = E + 2*p;
    float* Sp = S + 2*p;
    float2 bA[16], bB[16];
    #pragma unroll
    for (int j = 0; j < 16; ++j) bA[j] = *reinterpret_cast<const float2*>(Ep + (size_t)j*512);
    for (int bb = 0; bb < 8; ++bb) {
        const int b0 = 2*bb, b1 = 2*bb + 1;
        #pragma unroll
        for (int j = 0; j < 16; ++j)
            bB[j] = *reinterpret_cast<const float2*>(Ep + (size_t)(b1*16 + j)*512);
        #pragma unroll
        for (int j = 0; j < 16; ++j) {
            const int c = b0*16 + j + 1;
            float n0 = fLc*s0 - fLs*s1 + bA[j].x;
            float n1 = fLs*s0 + fLc*s1 + bA[j].y;
            s0 = n0; s1 = n1;
            *reinterpret_cast<float2*>(Sp + (size_t)c*512) = make_float2(s0, s1);
        }
        if (b1 + 1 < 16) {
            #pragma unroll
            for (int j = 0; j < 16; ++j)
                bA[j] = *reinterpret_cast<const float2*>(Ep + (size_t)((b1 + 1)*16 + j)*512);
        }
        #pragma unroll
        for (int j = 0; j < 16; ++j) {
            const int c = b1*16 + j + 1;
            float n0 = fLc*s0 - fLs*s1 + bB[j].x;
            float n1 = fLs*s0 + fLc*s1 + bB[j].y;
            s0 = n0; s1 = n1;
            if (c < NCHUNK)
                *reinterpret_cast<float2*>(Sp + (size_t)c*512) = make_float2(s0, s1);
        }
    }
}

// ---------------------------------------------------------------------------
extern "C" void kernel_launch(void* const* d_in, const int* in_sizes, int n_in,
                              void* d_out, int out_size, void* d_ws, size_t ws_size,
                              hipStream_t stream) {
    const float* X  = (const float*)d_in[0];  // (8,1,512,1,4096); batch 0 = first 2M floats
    const float* th = (const float*)d_in[1];
    const float* P  = (const float*)d_in[2];
    const float* Bm = (const float*)d_in[3];
    const float* C  = (const float*)d_in[4];
    const float* Dv = (const float*)d_in[5];
    const float* gl = (const float*)d_in[6];
    char* wsb = (char*)d_ws;
    float* ws   = (float*)wsb;
    u16*   W1pk = (u16*)(wsb + 32768);
    u16*   CEpk = (u16*)(wsb + 1081344);
    u16*   XTpk = (u16*)(wsb + 2129920);
    float* U    = (float*)(wsb + 10518528);
    float* E    = (float*)(wsb + 18907136);
    float* S    = (float*)(wsb + 19431424);
    float* TAB  = (float*)(wsb + 19955712);
    float* out  = (float*)d_out;

    k_setup<<<NHEADS, 64, 0, stream>>>(P, Bm, th, gl, ws);
    k_proj<<<2048, 256, 0, stream>>>(Bm, C, ws, W1pk, CEpk);
    k_xt<<<dim3(64, 8), 256, 0, stream>>>(X, XTpk);
    k_gemm<0><<<512, 256, 0, stream>>>(XTpk, (const float*)0, W1pk, U, XTpk, Dv, ws, E, S, TAB);
    k_carry<<<1, 256, 0, stream>>>(E, S, TAB, th, gl);
    k_gemm<1><<<512, 256, 0, stream>>>((const u16*)0, U, CEpk, out, XTpk, Dv, ws, E, S, TAB);
}

// Round 5
// 149.089 us; speedup vs baseline: 1.5845x; 1.0799x over previous
//
#include <hip/hip_runtime.h>
#include <math.h>

// Problem constants
#define NHEADS   64
#define TLEN     4096
#define CHUNK    16
#define NCHUNK   256  // TLEN / CHUNK

typedef unsigned short u16;
typedef unsigned int   u32;
typedef __attribute__((ext_vector_type(8))) short bf16x8;   // 8 bf16 in 4 VGPRs
typedef __attribute__((ext_vector_type(4))) float f32x4;

__device__ __forceinline__ u16 f2bf(float x) {               // RNE f32->bf16
    u32 u = __float_as_uint(x);
    u32 r = (u + 0x7FFFu + ((u >> 16) & 1u)) >> 16;
    return (u16)r;
}
__device__ __forceinline__ float bf2f(u16 h) { return __uint_as_float(((u32)h) << 16); }

// ws layout (BYTE offsets)
//  params f32 : 0        (Pm 4096 f, gamma @4096, theta @4160, norm @4416)
//  W1pk  u16  : 32768    512 rows x (512 hi + 512 lo)          (1 MB)
//  CEpk  u16  : 1081344  512 rows x (512 hi + 512 lo)          (1 MB)
//  XTpk  u16  : 2129920  4096 rows x (512 hi + 512 lo)         (8 MB)
//  U     f32  : 10518528 4096 x 512 (scanned local states)     (8 MB)
//  E     f32  : 18907136 256 x 512                             (512 KB)
//  S     f32  : 19431424 256 x 512                             (512 KB)
//  TAB   f32  : 19955712 16 x 256 x 2                          (32 KB)

// ---------------------------------------------------------------------------
// Kernel 1 (merged): blocks 0..511 transpose+pack X; blocks 512..575 do
// per-head setup (expm via fp64 scaling-and-squaring Taylor).
__global__ void k_pre(const float* __restrict__ X, u16* __restrict__ XT,
                      const float* __restrict__ P,
                      const float* __restrict__ Bmat,
                      const float* __restrict__ theta_log,
                      const float* __restrict__ gamma_log,
                      float* __restrict__ ws) {
    const int tid = threadIdx.x;
    if (blockIdx.x < 512) {
        // ---- X[d][t] -> XTpk[t]{hi[512],lo[512]} ----
        __shared__ float Xs[64][65];
        const int t0 = (blockIdx.x & 63) * 64, d0 = (blockIdx.x >> 6) * 64;
        {
            const int dr = tid >> 4, tc = (tid & 15) * 4;
            #pragma unroll
            for (int it = 0; it < 4; ++it) {
                const int dd = it*16 + dr;
                float4 v = *reinterpret_cast<const float4*>(X + (size_t)(d0 + dd)*4096 + t0 + tc);
                Xs[dd][tc] = v.x; Xs[dd][tc+1] = v.y; Xs[dd][tc+2] = v.z; Xs[dd][tc+3] = v.w;
            }
        }
        __syncthreads();
        const int tr = tid >> 2, ds = (tid & 3) * 16;
        u32 hb[8], lb[8];
        #pragma unroll
        for (int j = 0; j < 16; j += 2) {
            float a = Xs[ds + j][tr], b = Xs[ds + j + 1][tr];
            u16 ha = f2bf(a), la = f2bf(a - bf2f(ha));
            u16 hbb = f2bf(b), lbb = f2bf(b - bf2f(hbb));
            hb[j >> 1] = (u32)ha | ((u32)hbb << 16);
            lb[j >> 1] = (u32)la | ((u32)lbb << 16);
        }
        u16* orow = XT + (size_t)(t0 + tr)*1024 + d0 + ds;
        uint4 h0; h0.x = hb[0]; h0.y = hb[1]; h0.z = hb[2]; h0.w = hb[3];
        uint4 h1; h1.x = hb[4]; h1.y = hb[5]; h1.z = hb[6]; h1.w = hb[7];
        uint4 l0; l0.x = lb[0]; l0.y = lb[1]; l0.z = lb[2]; l0.w = lb[3];
        uint4 l1; l1.x = lb[4]; l1.y = lb[5]; l1.z = lb[6]; l1.w = lb[7];
        *reinterpret_cast<uint4*>(orow)       = h0;
        *reinterpret_cast<uint4*>(orow + 8)   = h1;
        *reinterpret_cast<uint4*>(orow + 512) = l0;
        *reinterpret_cast<uint4*>(orow + 520) = l1;
        return;
    }
    // ---- per-head setup ----
    __shared__ double As[8][8];
    __shared__ double Rs[8][8];
    __shared__ double red[256];
    __shared__ int sh_s;
    const int h = blockIdx.x - 512;
    const int i = (tid & 63) >> 3, j = tid & 7;
    const bool act = tid < 64;

    if (act)
        As[i][j] = (double)P[(h*8 + i)*8 + j] - (double)P[(h*8 + j)*8 + i];

    // trace(B B^T): 256 threads x 16 elems, coalesced
    const float* Bh = Bmat + h*8*512;
    double ss = 0.0;
    #pragma unroll
    for (int q = 0; q < 16; ++q) { float v = Bh[q*256 + tid]; ss += (double)v * (double)v; }
    red[tid] = ss;
    __syncthreads();

    if (tid == 0) {
        double nrm = 0.0;
        for (int r = 0; r < 8; ++r) {
            double rs = 0.0;
            for (int c = 0; c < 8; ++c) rs += fabs(As[r][c]);
            nrm = fmax(nrm, rs);
        }
        int s = 0;
        while (nrm > 0.25 && s < 40) { nrm *= 0.5; ++s; }
        sh_s = s;
        double tr = 0.0;
        for (int q = 0; q < 256; ++q) tr += red[q];
        double ed = exp((double)gamma_log[h]);
        double g  = exp(-ed);
        ws[4096 + h] = (float)g;
        ws[4416 + h] = (float)sqrt((1.0 - g*g) / tr);
    }
    if (tid < 4) ws[4160 + h*4 + tid] = expf(theta_log[h*4 + tid]);
    __syncthreads();

    const int NT = 13;
    if (act) {
        const double sc = ldexp(1.0, -sh_s);
        As[i][j] *= sc;
        Rs[i][j] = (i == j ? 1.0 : 0.0) + As[i][j] / (double)NT;
    }
    __syncthreads();
    for (int k = NT - 1; k >= 1; --k) {
        double t = 0.0;
        if (act) {
            #pragma unroll
            for (int m = 0; m < 8; ++m) t += As[i][m] * Rs[m][j];
        }
        __syncthreads();
        if (act) Rs[i][j] = (i == j ? 1.0 : 0.0) + t / (double)k;
        __syncthreads();
    }
    const int nsq = sh_s;
    for (int q = 0; q < nsq; ++q) {
        double t = 0.0;
        if (act) {
            #pragma unroll
            for (int m = 0; m < 8; ++m) t += Rs[i][m] * Rs[m][j];
        }
        __syncthreads();
        if (act) Rs[i][j] = t;
        __syncthreads();
    }
    if (act) ws[h*64 + i*8 + j] = (float)Rs[i][j];
}

// ---------------------------------------------------------------------------
// Kernel 2: fold Pm into B (-> W1pk[k][d]) and C (-> CEpk[e][k]), pack hi/lo bf16.
__global__ void k_proj(const float* __restrict__ Bmat,
                       const float* __restrict__ C,
                       const float* __restrict__ ws_ro,
                       u16* __restrict__ W1pk,
                       u16* __restrict__ CEpk) {
    const int gid = blockIdx.x * 256 + threadIdx.x;
    if (gid < 512*512) {
        const int k = gid >> 9, d = gid & 511;
        const int h = k >> 3, N = k & 7;
        const float* Pm = ws_ro + h*64 + N*8;
        const float nrm = ws_ro[4416 + h];
        float acc = 0.f;
        #pragma unroll
        for (int n = 0; n < 8; ++n) acc += Pm[n] * Bmat[(h*8 + n)*512 + d];
        acc *= nrm;
        u16 hi = f2bf(acc), lo = f2bf(acc - bf2f(hi));
        W1pk[k*1024 + d] = hi;
        W1pk[k*1024 + 512 + d] = lo;
    } else {
        const int g2 = gid - 512*512;
        const int e = g2 >> 9, k = g2 & 511;
        const int h = k >> 3, N = k & 7;
        const float* Pm = ws_ro + h*64 + N*8;
        float acc = 0.f;
        #pragma unroll
        for (int n = 0; n < 8; ++n) acc += Pm[n] * C[e*512 + h*8 + n];
        u16 hi = f2bf(acc), lo = f2bf(acc - bf2f(hi));
        CEpk[e*1024 + k] = hi;
        CEpk[e*1024 + 512 + k] = lo;
    }
}

// ---------------------------------------------------------------------------
// Kernel 3/5: split-bf16 MFMA GEMM, 64x64 tile, 4 waves 2x2, BK=64, with
// single-buffer register prefetch (loads for step s+1 issue under step s MFMA).
// MODE 0: A = XTpk; epilogue = in-LDS local scan -> U + E.
// MODE 1: A = U f32 + carry fixup during staging; epilogue = +D*x -> out.
#define MFMA_BF16(A_, B_, C_) __builtin_amdgcn_mfma_f32_16x16x32_bf16(A_, B_, C_, 0, 0, 0)
template<int MODE>
__global__ __launch_bounds__(256) void k_gemm(const u16* __restrict__ Apk,
                                              const float* __restrict__ Af,
                                              const u16* __restrict__ Bpk,
                                              float* __restrict__ Cout,
                                              const u16* __restrict__ XT,
                                              const float* __restrict__ Dvec,
                                              const float* __restrict__ wsro,
                                              float* __restrict__ E,
                                              const float* __restrict__ S,
                                              const float* __restrict__ TAB) {
    __shared__ char smem[36864];
    u16* Ah = (u16*)smem;          // 64 rows x 72 u16
    u16* Al = Ah + 4608;
    u16* Bh = Al + 4608;
    u16* Bl = Bh + 4608;
    float* Ut = (float*)smem;      // MODE0 epilogue: 64 x 72 f32 (= Ah..Bh area)

    const int tid = threadIdx.x;
    const int bid = blockIdx.x;
    const int tile = (bid & 7) * 64 + (bid >> 3);   // XCD-chunked swizzle
    const int mt = tile >> 3, nt = tile & 7;
    const int m0 = mt * 64, n0 = nt * 64;
    const int lane = tid & 63, wid = tid >> 6;
    const int wm = wid >> 1, wn = wid & 1;
    const int lr = lane & 15, lc = lane >> 4;
    const int sr = tid >> 2, ss = (tid & 3) * 16;   // staging: row, 16-elem seg

    f32x4 acc00 = {0.f,0.f,0.f,0.f}, acc01 = acc00, acc10 = acc00, acc11 = acc00;

    const int tA = m0 + sr;                 // staging row (t index)
    const int cA = tA >> 4, iA = tA & 15;   // chunk, offset (MODE1 fix)
    const u16* Brow = Bpk + (size_t)(n0 + sr)*1024 + ss;
    const u16* Arow = (MODE == 0) ? (Apk + (size_t)tA*1024 + ss) : (const u16*)0;
    const float* Urow = (MODE == 1) ? (Af + (size_t)tA*512 + ss) : (const float*)0;

    float4 rb0, rb1, rb2, rb3;              // B prefetch regs
    float4 ra0, ra1, ra2, ra3;              // MODE0 A prefetch
    float4 ru[4], rtb[4], rsv[4];           // MODE1 A prefetch

    // ---- prologue: load step 0 ----
    {
        const int k0 = 0;
        rb0 = *reinterpret_cast<const float4*>(Brow + k0);
        rb1 = *reinterpret_cast<const float4*>(Brow + k0 + 8);
        rb2 = *reinterpret_cast<const float4*>(Brow + 512 + k0);
        rb3 = *reinterpret_cast<const float4*>(Brow + 512 + k0 + 8);
        if constexpr (MODE == 0) {
            ra0 = *reinterpret_cast<const float4*>(Arow + k0);
            ra1 = *reinterpret_cast<const float4*>(Arow + k0 + 8);
            ra2 = *reinterpret_cast<const float4*>(Arow + 512 + k0);
            ra3 = *reinterpret_cast<const float4*>(Arow + 512 + k0 + 8);
        } else {
            const int p0 = (k0 + ss) >> 1;
            #pragma unroll
            for (int j = 0; j < 4; ++j) {
                ru[j]  = *reinterpret_cast<const float4*>(Urow + k0 + 4*j);
                rtb[j] = *reinterpret_cast<const float4*>(TAB + ((size_t)iA*256 + p0 + 2*j)*2);
                rsv[j] = *reinterpret_cast<const float4*>(S + (size_t)cA*512 + 2*p0 + 4*j);
            }
        }
    }

    for (int s = 0; s < 8; ++s) {
        // ---- stage current regs into LDS ----
        if constexpr (MODE == 0) {
            *reinterpret_cast<float4*>(&Ah[sr*72 + ss])     = ra0;
            *reinterpret_cast<float4*>(&Ah[sr*72 + ss + 8]) = ra1;
            *reinterpret_cast<float4*>(&Al[sr*72 + ss])     = ra2;
            *reinterpret_cast<float4*>(&Al[sr*72 + ss + 8]) = ra3;
        } else {
            #pragma unroll
            for (int j = 0; j < 4; ++j) {
                float4 u = ru[j], tb = rtb[j], sv = rsv[j];
                u.x += tb.x*sv.x - tb.y*sv.y;
                u.y += tb.y*sv.x + tb.x*sv.y;
                u.z += tb.z*sv.z - tb.w*sv.w;
                u.w += tb.w*sv.z + tb.z*sv.w;
                u16 hx = f2bf(u.x), hy = f2bf(u.y), hz = f2bf(u.z), hw = f2bf(u.w);
                u16 lx = f2bf(u.x - bf2f(hx)), ly = f2bf(u.y - bf2f(hy));
                u16 lz = f2bf(u.z - bf2f(hz)), lw = f2bf(u.w - bf2f(hw));
                uint2 wh; wh.x = (u32)hx | ((u32)hy << 16); wh.y = (u32)hz | ((u32)hw << 16);
                uint2 wl; wl.x = (u32)lx | ((u32)ly << 16); wl.y = (u32)lz | ((u32)lw << 16);
                *reinterpret_cast<uint2*>(&Ah[sr*72 + ss + 4*j]) = wh;
                *reinterpret_cast<uint2*>(&Al[sr*72 + ss + 4*j]) = wl;
            }
        }
        *reinterpret_cast<float4*>(&Bh[sr*72 + ss])     = rb0;
        *reinterpret_cast<float4*>(&Bh[sr*72 + ss + 8]) = rb1;
        *reinterpret_cast<float4*>(&Bl[sr*72 + ss])     = rb2;
        *reinterpret_cast<float4*>(&Bl[sr*72 + ss + 8]) = rb3;
        __syncthreads();

        // ---- issue next step's loads (latency hides under MFMA) ----
        if (s < 7) {
            const int k0 = (s + 1) * 64;
            rb0 = *reinterpret_cast<const float4*>(Brow + k0);
            rb1 = *reinterpret_cast<const float4*>(Brow + k0 + 8);
            rb2 = *reinterpret_cast<const float4*>(Brow + 512 + k0);
            rb3 = *reinterpret_cast<const float4*>(Brow + 512 + k0 + 8);
            if constexpr (MODE == 0) {
                ra0 = *reinterpret_cast<const float4*>(Arow + k0);
                ra1 = *reinterpret_cast<const float4*>(Arow + k0 + 8);
                ra2 = *reinterpret_cast<const float4*>(Arow + 512 + k0);
                ra3 = *reinterpret_cast<const float4*>(Arow + 512 + k0 + 8);
            } else {
                const int p0 = (k0 + ss) >> 1;
                #pragma unroll
                for (int j = 0; j < 4; ++j) {
                    ru[j]  = *reinterpret_cast<const float4*>(Urow + k0 + 4*j);
                    rtb[j] = *reinterpret_cast<const float4*>(TAB + ((size_t)iA*256 + p0 + 2*j)*2);
                    rsv[j] = *reinterpret_cast<const float4*>(S + (size_t)cA*512 + 2*p0 + 4*j);
                }
            }
        }

        // ---- MFMA on staged LDS ----
        #pragma unroll
        for (int kk = 0; kk < 2; ++kk) {
            const int ko = kk*32 + lc*8;
            const int ra0i = (wm*32 + lr)*72 + ko,  ra1i = ra0i + 16*72;
            const int rb0i = (wn*32 + lr)*72 + ko,  rb1i = rb0i + 16*72;
            bf16x8 fah0 = *reinterpret_cast<const bf16x8*>(&Ah[ra0i]);
            bf16x8 fah1 = *reinterpret_cast<const bf16x8*>(&Ah[ra1i]);
            bf16x8 fal0 = *reinterpret_cast<const bf16x8*>(&Al[ra0i]);
            bf16x8 fal1 = *reinterpret_cast<const bf16x8*>(&Al[ra1i]);
            bf16x8 fbh0 = *reinterpret_cast<const bf16x8*>(&Bh[rb0i]);
            bf16x8 fbh1 = *reinterpret_cast<const bf16x8*>(&Bh[rb1i]);
            bf16x8 fbl0 = *reinterpret_cast<const bf16x8*>(&Bl[rb0i]);
            bf16x8 fbl1 = *reinterpret_cast<const bf16x8*>(&Bl[rb1i]);
            acc00 = MFMA_BF16(fah0, fbl0, acc00);
            acc00 = MFMA_BF16(fal0, fbh0, acc00);
            acc00 = MFMA_BF16(fah0, fbh0, acc00);
            acc01 = MFMA_BF16(fah0, fbl1, acc01);
            acc01 = MFMA_BF16(fal0, fbh1, acc01);
            acc01 = MFMA_BF16(fah0, fbh1, acc01);
            acc10 = MFMA_BF16(fah1, fbl0, acc10);
            acc10 = MFMA_BF16(fal1, fbh0, acc10);
            acc10 = MFMA_BF16(fah1, fbh0, acc10);
            acc11 = MFMA_BF16(fah1, fbl1, acc11);
            acc11 = MFMA_BF16(fal1, fbh1, acc11);
            acc11 = MFMA_BF16(fah1, fbh1, acc11);
        }
        __syncthreads();
    }

    if constexpr (MODE == 0) {
        // ---- fused local scan epilogue ----
        #pragma unroll
        for (int im = 0; im < 2; ++im) {
            #pragma unroll
            for (int in = 0; in < 2; ++in) {
                f32x4 v = (im == 0) ? (in == 0 ? acc00 : acc01)
                                    : (in == 0 ? acc10 : acc11);
                const int row0 = wm*32 + im*16 + lc*4;
                const int col  = wn*32 + in*16 + lr;
                #pragma unroll
                for (int rg = 0; rg < 4; ++rg)
                    Ut[(row0 + rg)*72 + col] = v[rg];
            }
        }
        __syncthreads();
        if (tid < 128) {
            const int cc = tid >> 5, pp = tid & 31;   // local chunk 0..3, local pair
            const int pg = nt*32 + pp;                // global pair
            const float th = wsro[4160 + pg];
            const float g  = wsro[4096 + (pg >> 2)];
            const float cs = cosf(th), sn = sinf(th);
            float h0 = 0.f, h1 = 0.f;
            float* col = Ut + (cc*16)*72 + 2*pp;
            #pragma unroll
            for (int i = 0; i < CHUNK; ++i) {
                float a = col[i*72], b = col[i*72 + 1];
                float n0v = g*(cs*h0 - sn*h1) + a;
                float n1v = g*(sn*h0 + cs*h1) + b;
                col[i*72] = n0v; col[i*72 + 1] = n1v;
                h0 = n0v; h1 = n1v;
            }
            E[(size_t)(mt*4 + cc)*512 + 2*pg]     = h0;
            E[(size_t)(mt*4 + cc)*512 + 2*pg + 1] = h1;
        }
        __syncthreads();
        const int row = tid >> 2, cseg = (tid & 3) * 16;
        #pragma unroll
        for (int j = 0; j < 4; ++j) {
            float4 v = *reinterpret_cast<const float4*>(&Ut[row*72 + cseg + 4*j]);
            *reinterpret_cast<float4*>(Cout + (size_t)(m0 + row)*512 + n0 + cseg + 4*j) = v;
        }
    } else {
        // ---- D*x epilogue ----
        #pragma unroll
        for (int im = 0; im < 2; ++im) {
            #pragma unroll
            for (int in = 0; in < 2; ++in) {
                f32x4 v = (im == 0) ? (in == 0 ? acc00 : acc01)
                                    : (in == 0 ? acc10 : acc11);
                const int row0 = m0 + wm*32 + im*16 + lc*4;
                const int col  = n0 + wn*32 + in*16 + lr;
                const float dv = Dvec[col];
                #pragma unroll
                for (int rg = 0; rg < 4; ++rg) {
                    const int t = row0 + rg;
                    float xv = bf2f(XT[(size_t)t*1024 + col]) + bf2f(XT[(size_t)t*1024 + 512 + col]);
                    Cout[(size_t)t*512 + col] = v[rg] + dv*xv;
                }
            }
        }
    }
}

// ---------------------------------------------------------------------------
// Kernel 4: wave-parallel carry. One wave per pair p; lane l owns chunks
// 4l..4l+3. Chunk-step operator L = gamma^16 R(16*theta); scan multipliers
// L^{4*2^d} computed in closed form (fp64). Also emits TAB in closed form.
__global__ void k_carry(const float* __restrict__ E, float* __restrict__ S,
                        float* __restrict__ TAB,
                        const float* __restrict__ theta_log,
                        const float* __restrict__ gamma_log) {
    const int w = threadIdx.x >> 6, l = threadIdx.x & 63;
    const int p = blockIdx.x*4 + w;
    const double th = exp((double)theta_log[p]);
    const double ed = exp((double)gamma_log[p >> 2]);

    if (l < CHUNK) {   // TAB[i] = gamma^{i+1} * (cos,sin)((i+1)theta)
        double a = (double)(l + 1) * th;
        double g = exp(-(double)(l + 1) * ed);
        TAB[((size_t)l*256 + p)*2 + 0] = (float)(g * cos(a));
        TAB[((size_t)l*256 + p)*2 + 1] = (float)(g * sin(a));
    }

    const double a16 = 16.0*th, g16 = exp(-16.0*ed);
    const float Lc = (float)(g16*cos(a16)), Ls = (float)(g16*sin(a16));

    const float* Ep = E + 2*p;
    float2 e0 = *reinterpret_cast<const float2*>(Ep + (size_t)(4*l + 0)*512);
    float2 e1 = *reinterpret_cast<const float2*>(Ep + (size_t)(4*l + 1)*512);
    float2 e2 = *reinterpret_cast<const float2*>(Ep + (size_t)(4*l + 2)*512);
    float2 e3 = *reinterpret_cast<const float2*>(Ep + (size_t)(4*l + 3)*512);

    // lane-local inclusive combine of 4 chunks
    float2 v = e0;
    v = make_float2(Lc*v.x - Ls*v.y + e1.x, Ls*v.x + Lc*v.y + e1.y);
    v = make_float2(Lc*v.x - Ls*v.y + e2.x, Ls*v.x + Lc*v.y + e2.y);
    v = make_float2(Lc*v.x - Ls*v.y + e3.x, Ls*v.x + Lc*v.y + e3.y);

    // wave inclusive scan: v(l) = state after chunk 4l+3
    #pragma unroll
    for (int d = 0; d < 6; ++d) {
        const int sh = 1 << d;
        const double aa = 64.0 * (double)sh * th;
        const double gg = exp(-64.0 * (double)sh * ed);
        const float Mc = (float)(gg*cos(aa)), Ms = (float)(gg*sin(aa));
        float px = __shfl_up(v.x, sh, 64);
        float py = __shfl_up(v.y, sh, 64);
        if (l >= sh) {
            v.x += Mc*px - Ms*py;
            v.y += Ms*px + Mc*py;
        }
    }

    // carries into chunks 4l..4l+3
    float sx = __shfl_up(v.x, 1, 64), sy = __shfl_up(v.y, 1, 64);
    float2 s = (l == 0) ? make_float2(0.f, 0.f) : make_float2(sx, sy);
    float* Sp = S + 2*p;
    *reinterpret_cast<float2*>(Sp + (size_t)(4*l + 0)*512) = s;
    s = make_float2(Lc*s.x - Ls*s.y + e0.x, Ls*s.x + Lc*s.y + e0.y);
    *reinterpret_cast<float2*>(Sp + (size_t)(4*l + 1)*512) = s;
    s = make_float2(Lc*s.x - Ls*s.y + e1.x, Ls*s.x + Lc*s.y + e1.y);
    *reinterpret_cast<float2*>(Sp + (size_t)(4*l + 2)*512) = s;
    s = make_float2(Lc*s.x - Ls*s.y + e2.x, Ls*s.x + Lc*s.y + e2.y);
    *reinterpret_cast<float2*>(Sp + (size_t)(4*l + 3)*512) = s;
}

// ---------------------------------------------------------------------------
extern "C" void kernel_launch(void* const* d_in, const int* in_sizes, int n_in,
                              void* d_out, int out_size, void* d_ws, size_t ws_size,
                              hipStream_t stream) {
    const float* X  = (const float*)d_in[0];  // (8,1,512,1,4096); batch 0 = first 2M floats
    const float* th = (const float*)d_in[1];
    const float* P  = (const float*)d_in[2];
    const float* Bm = (const float*)d_in[3];
    const float* C  = (const float*)d_in[4];
    const float* Dv = (const float*)d_in[5];
    const float* gl = (const float*)d_in[6];
    char* wsb = (char*)d_ws;
    float* ws   = (float*)wsb;
    u16*   W1pk = (u16*)(wsb + 32768);
    u16*   CEpk = (u16*)(wsb + 1081344);
    u16*   XTpk = (u16*)(wsb + 2129920);
    float* U    = (float*)(wsb + 10518528);
    float* E    = (float*)(wsb + 18907136);
    float* S    = (float*)(wsb + 19431424);
    float* TAB  = (float*)(wsb + 19955712);
    float* out  = (float*)d_out;

    k_pre<<<576, 256, 0, stream>>>(X, XTpk, P, Bm, th, gl, ws);
    k_proj<<<2048, 256, 0, stream>>>(Bm, C, ws, W1pk, CEpk);
    k_gemm<0><<<512, 256, 0, stream>>>(XTpk, (const float*)0, W1pk, U, XTpk, Dv, ws, E, S, TAB);
    k_carry<<<64, 256, 0, stream>>>(E, S, TAB, th, gl);
    k_gemm<1><<<512, 256, 0, stream>>>((const u16*)0, U, CEpk, out, XTpk, Dv, ws, E, S, TAB);
}

// Round 6
// 149.057 us; speedup vs baseline: 1.5848x; 1.0002x over previous
//
#include <hip/hip_runtime.h>
#include <math.h>

// Problem constants
#define NHEADS   64
#define TLEN     4096
#define CHUNK    16
#define NCHUNK   256  // TLEN / CHUNK

typedef unsigned short u16;
typedef unsigned int   u32;
typedef __attribute__((ext_vector_type(8))) short bf16x8;   // 8 bf16 in 4 VGPRs
typedef __attribute__((ext_vector_type(4))) float f32x4;

__device__ __forceinline__ u16 f2bf(float x) {               // RNE f32->bf16
    u32 u = __float_as_uint(x);
    u32 r = (u + 0x7FFFu + ((u >> 16) & 1u)) >> 16;
    return (u16)r;
}
__device__ __forceinline__ float bf2f(u16 h) { return __uint_as_float(((u32)h) << 16); }
__device__ __forceinline__ u16 f2bf_trunc(float x) { return (u16)(__float_as_uint(x) >> 16); }

// ws layout (BYTE offsets)
//  params f32 : 0        (Pm 4096 f, gamma @4096, theta @4160, norm @4416)
//  W1pk  u16  : 32768    512 rows x (512 hi + 512 lo)          (1 MB)
//  CEpk  u16  : 1081344  512 rows x (512 hi + 512 lo)          (1 MB)
//  XTpk  u16  : 2129920  4096 rows x (512 hi + 512 lo)         (8 MB)
//  U     f32  : 10518528 4096 x 512 (scanned local states)     (8 MB)
//  E     f32  : 18907136 256 x 512                             (512 KB)
//  S     f32  : 19431424 256 x 512                             (512 KB)
//  TAB   f32  : 19955712 16 x 256 x 2                          (32 KB)

// ---------------------------------------------------------------------------
// Kernel 1 (merged): blocks 0..511 transpose+pack X; blocks 512..575 do
// per-head setup (expm via fp64 scaling-and-squaring Taylor).
__global__ void k_pre(const float* __restrict__ X, u16* __restrict__ XT,
                      const float* __restrict__ P,
                      const float* __restrict__ Bmat,
                      const float* __restrict__ theta_log,
                      const float* __restrict__ gamma_log,
                      float* __restrict__ ws) {
    const int tid = threadIdx.x;
    if (blockIdx.x < 512) {
        // ---- X[d][t] -> XTpk[t]{hi[512],lo[512]} ----
        __shared__ float Xs[64][65];
        const int t0 = (blockIdx.x & 63) * 64, d0 = (blockIdx.x >> 6) * 64;
        {
            const int dr = tid >> 4, tc = (tid & 15) * 4;
            #pragma unroll
            for (int it = 0; it < 4; ++it) {
                const int dd = it*16 + dr;
                float4 v = *reinterpret_cast<const float4*>(X + (size_t)(d0 + dd)*4096 + t0 + tc);
                Xs[dd][tc] = v.x; Xs[dd][tc+1] = v.y; Xs[dd][tc+2] = v.z; Xs[dd][tc+3] = v.w;
            }
        }
        __syncthreads();
        const int tr = tid >> 2, ds = (tid & 3) * 16;
        u32 hb[8], lb[8];
        #pragma unroll
        for (int j = 0; j < 16; j += 2) {
            float a = Xs[ds + j][tr], b = Xs[ds + j + 1][tr];
            u16 ha = f2bf(a), la = f2bf(a - bf2f(ha));
            u16 hbb = f2bf(b), lbb = f2bf(b - bf2f(hbb));
            hb[j >> 1] = (u32)ha | ((u32)hbb << 16);
            lb[j >> 1] = (u32)la | ((u32)lbb << 16);
        }
        u16* orow = XT + (size_t)(t0 + tr)*1024 + d0 + ds;
        uint4 h0; h0.x = hb[0]; h0.y = hb[1]; h0.z = hb[2]; h0.w = hb[3];
        uint4 h1; h1.x = hb[4]; h1.y = hb[5]; h1.z = hb[6]; h1.w = hb[7];
        uint4 l0; l0.x = lb[0]; l0.y = lb[1]; l0.z = lb[2]; l0.w = lb[3];
        uint4 l1; l1.x = lb[4]; l1.y = lb[5]; l1.z = lb[6]; l1.w = lb[7];
        *reinterpret_cast<uint4*>(orow)       = h0;
        *reinterpret_cast<uint4*>(orow + 8)   = h1;
        *reinterpret_cast<uint4*>(orow + 512) = l0;
        *reinterpret_cast<uint4*>(orow + 520) = l1;
        return;
    }
    // ---- per-head setup ----
    __shared__ double As[8][8];
    __shared__ double Rs[8][8];
    __shared__ double red[256];
    __shared__ int sh_s;
    const int h = blockIdx.x - 512;
    const int i = (tid & 63) >> 3, j = tid & 7;
    const bool act = tid < 64;

    if (act)
        As[i][j] = (double)P[(h*8 + i)*8 + j] - (double)P[(h*8 + j)*8 + i];

    const float* Bh = Bmat + h*8*512;
    double ss = 0.0;
    #pragma unroll
    for (int q = 0; q < 16; ++q) { float v = Bh[q*256 + tid]; ss += (double)v * (double)v; }
    red[tid] = ss;
    __syncthreads();

    if (tid == 0) {
        double nrm = 0.0;
        for (int r = 0; r < 8; ++r) {
            double rs = 0.0;
            for (int c = 0; c < 8; ++c) rs += fabs(As[r][c]);
            nrm = fmax(nrm, rs);
        }
        int s = 0;
        while (nrm > 0.25 && s < 40) { nrm *= 0.5; ++s; }
        sh_s = s;
        double tr = 0.0;
        for (int q = 0; q < 256; ++q) tr += red[q];
        double ed = exp((double)gamma_log[h]);
        double g  = exp(-ed);
        ws[4096 + h] = (float)g;
        ws[4416 + h] = (float)sqrt((1.0 - g*g) / tr);
    }
    if (tid < 4) ws[4160 + h*4 + tid] = expf(theta_log[h*4 + tid]);
    __syncthreads();

    const int NT = 13;
    if (act) {
        const double sc = ldexp(1.0, -sh_s);
        As[i][j] *= sc;
        Rs[i][j] = (i == j ? 1.0 : 0.0) + As[i][j] / (double)NT;
    }
    __syncthreads();
    for (int k = NT - 1; k >= 1; --k) {
        double t = 0.0;
        if (act) {
            #pragma unroll
            for (int m = 0; m < 8; ++m) t += As[i][m] * Rs[m][j];
        }
        __syncthreads();
        if (act) Rs[i][j] = (i == j ? 1.0 : 0.0) + t / (double)k;
        __syncthreads();
    }
    const int nsq = sh_s;
    for (int q = 0; q < nsq; ++q) {
        double t = 0.0;
        if (act) {
            #pragma unroll
            for (int m = 0; m < 8; ++m) t += Rs[i][m] * Rs[m][j];
        }
        __syncthreads();
        if (act) Rs[i][j] = t;
        __syncthreads();
    }
    if (act) ws[h*64 + i*8 + j] = (float)Rs[i][j];
}

// ---------------------------------------------------------------------------
// Kernel 2: fold Pm into B (-> W1pk[k][d]) and C (-> CEpk[e][k]), pack hi/lo bf16.
__global__ void k_proj(const float* __restrict__ Bmat,
                       const float* __restrict__ C,
                       const float* __restrict__ ws_ro,
                       u16* __restrict__ W1pk,
                       u16* __restrict__ CEpk) {
    const int gid = blockIdx.x * 256 + threadIdx.x;
    if (gid < 512*512) {
        const int k = gid >> 9, d = gid & 511;
        const int h = k >> 3, N = k & 7;
        const float* Pm = ws_ro + h*64 + N*8;
        const float nrm = ws_ro[4416 + h];
        float acc = 0.f;
        #pragma unroll
        for (int n = 0; n < 8; ++n) acc += Pm[n] * Bmat[(h*8 + n)*512 + d];
        acc *= nrm;
        u16 hi = f2bf(acc), lo = f2bf(acc - bf2f(hi));
        W1pk[k*1024 + d] = hi;
        W1pk[k*1024 + 512 + d] = lo;
    } else {
        const int g2 = gid - 512*512;
        const int e = g2 >> 9, k = g2 & 511;
        const int h = k >> 3, N = k & 7;
        const float* Pm = ws_ro + h*64 + N*8;
        float acc = 0.f;
        #pragma unroll
        for (int n = 0; n < 8; ++n) acc += Pm[n] * C[e*512 + h*8 + n];
        u16 hi = f2bf(acc), lo = f2bf(acc - bf2f(hi));
        CEpk[e*1024 + k] = hi;
        CEpk[e*1024 + 512 + k] = lo;
    }
}

// ---------------------------------------------------------------------------
// Kernel 3/5: split-bf16 MFMA GEMM, 64x64 tile, 4 waves 2x2, BK=64.
// DOUBLE-BUFFERED LDS: one barrier per k-step; reg prefetch of step s+1
// issued before step s's MFMA; stores for s+1 land after, into the other buf.
// MODE 0: A = XTpk; epilogue = in-LDS local scan -> U + E.
// MODE 1: A = U f32 + carry fixup during staging; epilogue = +D*x -> out.
#define MFMA_BF16(A_, B_, C_) __builtin_amdgcn_mfma_f32_16x16x32_bf16(A_, B_, C_, 0, 0, 0)
template<int MODE>
__global__ __launch_bounds__(256, 2) void k_gemm(const u16* __restrict__ Apk,
                                                 const float* __restrict__ Af,
                                                 const u16* __restrict__ Bpk,
                                                 float* __restrict__ Cout,
                                                 const u16* __restrict__ XT,
                                                 const float* __restrict__ Dvec,
                                                 const float* __restrict__ wsro,
                                                 float* __restrict__ E,
                                                 const float* __restrict__ S,
                                                 const float* __restrict__ TAB) {
    __shared__ char smem[73728];              // 2 x (Ah,Al,Bh,Bl of 9216 B)
    float* Ut = (float*)smem;                 // MODE0 epilogue scratch (18432 B)

    const int tid = threadIdx.x;
    const int bid = blockIdx.x;
    const int tile = (bid & 7) * 64 + (bid >> 3);   // XCD-chunked swizzle
    const int mt = tile >> 3, nt = tile & 7;
    const int m0 = mt * 64, n0 = nt * 64;
    const int lane = tid & 63, wid = tid >> 6;
    const int wm = wid >> 1, wn = wid & 1;
    const int lr = lane & 15, lc = lane >> 4;
    const int sr = tid >> 2, ss = (tid & 3) * 16;   // staging: row, 16-elem seg

    f32x4 acc00 = {0.f,0.f,0.f,0.f}, acc01 = acc00, acc10 = acc00, acc11 = acc00;

    const int tA = m0 + sr;                 // staging row (t index)
    const int cA = tA >> 4, iA = tA & 15;   // chunk, offset (MODE1 fix)
    const u16* Brow = Bpk + (size_t)(n0 + sr)*1024 + ss;
    const u16* Arow = (MODE == 0) ? (Apk + (size_t)tA*1024 + ss) : (const u16*)0;
    const float* Urow = (MODE == 1) ? (Af + (size_t)tA*512 + ss) : (const float*)0;

    float4 rb0, rb1, rb2, rb3;              // B prefetch regs
    float4 ra0, ra1, ra2, ra3;              // MODE0 A prefetch
    float4 ru[4], rtb[4], rsv[4];           // MODE1 A prefetch

    // macros as lambdas over compile-time buffer parity
    auto LOADREGS = [&](int k0) {
        rb0 = *reinterpret_cast<const float4*>(Brow + k0);
        rb1 = *reinterpret_cast<const float4*>(Brow + k0 + 8);
        rb2 = *reinterpret_cast<const float4*>(Brow + 512 + k0);
        rb3 = *reinterpret_cast<const float4*>(Brow + 512 + k0 + 8);
        if constexpr (MODE == 0) {
            ra0 = *reinterpret_cast<const float4*>(Arow + k0);
            ra1 = *reinterpret_cast<const float4*>(Arow + k0 + 8);
            ra2 = *reinterpret_cast<const float4*>(Arow + 512 + k0);
            ra3 = *reinterpret_cast<const float4*>(Arow + 512 + k0 + 8);
        } else {
            const int p0 = (k0 + ss) >> 1;
            #pragma unroll
            for (int j = 0; j < 4; ++j) {
                ru[j]  = *reinterpret_cast<const float4*>(Urow + k0 + 4*j);
                rtb[j] = *reinterpret_cast<const float4*>(TAB + ((size_t)iA*256 + p0 + 2*j)*2);
                rsv[j] = *reinterpret_cast<const float4*>(S + (size_t)cA*512 + 2*p0 + 4*j);
            }
        }
    };
    auto STORE = [&](u16* Ah, u16* Al, u16* Bh, u16* Bl) {
        if constexpr (MODE == 0) {
            *reinterpret_cast<float4*>(&Ah[sr*72 + ss])     = ra0;
            *reinterpret_cast<float4*>(&Ah[sr*72 + ss + 8]) = ra1;
            *reinterpret_cast<float4*>(&Al[sr*72 + ss])     = ra2;
            *reinterpret_cast<float4*>(&Al[sr*72 + ss + 8]) = ra3;
        } else {
            #pragma unroll
            for (int j = 0; j < 4; ++j) {
                float4 u = ru[j], tb = rtb[j], sv = rsv[j];
                u.x += tb.x*sv.x - tb.y*sv.y;
                u.y += tb.y*sv.x + tb.x*sv.y;
                u.z += tb.z*sv.z - tb.w*sv.w;
                u.w += tb.w*sv.z + tb.z*sv.w;
                u16 hx = f2bf(u.x), hy = f2bf(u.y), hz = f2bf(u.z), hw = f2bf(u.w);
                u16 lx = f2bf_trunc(u.x - bf2f(hx)), ly = f2bf_trunc(u.y - bf2f(hy));
                u16 lz = f2bf_trunc(u.z - bf2f(hz)), lw = f2bf_trunc(u.w - bf2f(hw));
                uint2 wh; wh.x = (u32)hx | ((u32)hy << 16); wh.y = (u32)hz | ((u32)hw << 16);
                uint2 wl; wl.x = (u32)lx | ((u32)ly << 16); wl.y = (u32)lz | ((u32)lw << 16);
                *reinterpret_cast<uint2*>(&Ah[sr*72 + ss + 4*j]) = wh;
                *reinterpret_cast<uint2*>(&Al[sr*72 + ss + 4*j]) = wl;
            }
        }
        *reinterpret_cast<float4*>(&Bh[sr*72 + ss])     = rb0;
        *reinterpret_cast<float4*>(&Bh[sr*72 + ss + 8]) = rb1;
        *reinterpret_cast<float4*>(&Bl[sr*72 + ss])     = rb2;
        *reinterpret_cast<float4*>(&Bl[sr*72 + ss + 8]) = rb3;
    };
    auto MFMAS = [&](const u16* Ah, const u16* Al, const u16* Bh, const u16* Bl) {
        #pragma unroll
        for (int kk = 0; kk < 2; ++kk) {
            const int ko = kk*32 + lc*8;
            const int ra0i = (wm*32 + lr)*72 + ko,  ra1i = ra0i + 16*72;
            const int rb0i = (wn*32 + lr)*72 + ko,  rb1i = rb0i + 16*72;
            bf16x8 fah0 = *reinterpret_cast<const bf16x8*>(&Ah[ra0i]);
            bf16x8 fah1 = *reinterpret_cast<const bf16x8*>(&Ah[ra1i]);
            bf16x8 fal0 = *reinterpret_cast<const bf16x8*>(&Al[ra0i]);
            bf16x8 fal1 = *reinterpret_cast<const bf16x8*>(&Al[ra1i]);
            bf16x8 fbh0 = *reinterpret_cast<const bf16x8*>(&Bh[rb0i]);
            bf16x8 fbh1 = *reinterpret_cast<const bf16x8*>(&Bh[rb1i]);
            bf16x8 fbl0 = *reinterpret_cast<const bf16x8*>(&Bl[rb0i]);
            bf16x8 fbl1 = *reinterpret_cast<const bf16x8*>(&Bl[rb1i]);
            acc00 = MFMA_BF16(fah0, fbl0, acc00);
            acc00 = MFMA_BF16(fal0, fbh0, acc00);
            acc00 = MFMA_BF16(fah0, fbh0, acc00);
            acc01 = MFMA_BF16(fah0, fbl1, acc01);
            acc01 = MFMA_BF16(fal0, fbh1, acc01);
            acc01 = MFMA_BF16(fah0, fbh1, acc01);
            acc10 = MFMA_BF16(fah1, fbl0, acc10);
            acc10 = MFMA_BF16(fal1, fbh0, acc10);
            acc10 = MFMA_BF16(fah1, fbh0, acc10);
            acc11 = MFMA_BF16(fah1, fbl1, acc11);
            acc11 = MFMA_BF16(fal1, fbh1, acc11);
            acc11 = MFMA_BF16(fah1, fbh1, acc11);
        }
    };

    u16* buf0 = (u16*)smem;
    u16* buf1 = (u16*)(smem + 36864);

    // prologue
    LOADREGS(0);
    STORE(buf0, buf0 + 4608, buf0 + 9216, buf0 + 13824);
    __syncthreads();

    #pragma unroll
    for (int s = 0; s < 8; ++s) {
        u16* bp = (s & 1) ? buf1 : buf0;
        u16* bq = (s & 1) ? buf0 : buf1;
        if (s < 7) LOADREGS((s + 1) * 64);
        MFMAS(bp, bp + 4608, bp + 9216, bp + 13824);
        if (s < 7) STORE(bq, bq + 4608, bq + 9216, bq + 13824);
        __syncthreads();
    }

    if constexpr (MODE == 0) {
        // ---- fused local scan epilogue (uses buf0 area as f32 scratch) ----
        #pragma unroll
        for (int im = 0; im < 2; ++im) {
            #pragma unroll
            for (int in = 0; in < 2; ++in) {
                f32x4 v = (im == 0) ? (in == 0 ? acc00 : acc01)
                                    : (in == 0 ? acc10 : acc11);
                const int row0 = wm*32 + im*16 + lc*4;
                const int col  = wn*32 + in*16 + lr;
                #pragma unroll
                for (int rg = 0; rg < 4; ++rg)
                    Ut[(row0 + rg)*72 + col] = v[rg];
            }
        }
        __syncthreads();
        if (tid < 128) {
            const int cc = tid >> 5, pp = tid & 31;   // local chunk 0..3, local pair
            const int pg = nt*32 + pp;                // global pair
            const float th = wsro[4160 + pg];
            const float g  = wsro[4096 + (pg >> 2)];
            const float cs = cosf(th), sn = sinf(th);
            float h0 = 0.f, h1 = 0.f;
            float* col = Ut + (cc*16)*72 + 2*pp;
            #pragma unroll
            for (int i = 0; i < CHUNK; ++i) {
                float a = col[i*72], b = col[i*72 + 1];
                float n0v = g*(cs*h0 - sn*h1) + a;
                float n1v = g*(sn*h0 + cs*h1) + b;
                col[i*72] = n0v; col[i*72 + 1] = n1v;
                h0 = n0v; h1 = n1v;
            }
            E[(size_t)(mt*4 + cc)*512 + 2*pg]     = h0;
            E[(size_t)(mt*4 + cc)*512 + 2*pg + 1] = h1;
        }
        __syncthreads();
        const int row = tid >> 2, cseg = (tid & 3) * 16;
        #pragma unroll
        for (int j = 0; j < 4; ++j) {
            float4 v = *reinterpret_cast<const float4*>(&Ut[row*72 + cseg + 4*j]);
            *reinterpret_cast<float4*>(Cout + (size_t)(m0 + row)*512 + n0 + cseg + 4*j) = v;
        }
    } else {
        // ---- D*x epilogue ----
        #pragma unroll
        for (int im = 0; im < 2; ++im) {
            #pragma unroll
            for (int in = 0; in < 2; ++in) {
                f32x4 v = (im == 0) ? (in == 0 ? acc00 : acc01)
                                    : (in == 0 ? acc10 : acc11);
                const int row0 = m0 + wm*32 + im*16 + lc*4;
                const int col  = n0 + wn*32 + in*16 + lr;
                const float dv = Dvec[col];
                #pragma unroll
                for (int rg = 0; rg < 4; ++rg) {
                    const int t = row0 + rg;
                    float xv = bf2f(XT[(size_t)t*1024 + col]) + bf2f(XT[(size_t)t*1024 + 512 + col]);
                    Cout[(size_t)t*512 + col] = v[rg] + dv*xv;
                }
            }
        }
    }
}

// ---------------------------------------------------------------------------
// Kernel 4: wave-parallel carry. One wave per pair p; lane l owns chunks
// 4l..4l+3. Chunk-step operator L = gamma^16 R(16*theta); scan multipliers
// L^{4*2^d} computed in closed form (fp64). Also emits TAB in closed form.
__global__ void k_carry(const float* __restrict__ E, float* __restrict__ S,
                        float* __restrict__ TAB,
                        const float* __restrict__ theta_log,
                        const float* __restrict__ gamma_log) {
    const int w = threadIdx.x >> 6, l = threadIdx.x & 63;
    const int p = blockIdx.x*4 + w;
    const double th = exp((double)theta_log[p]);
    const double ed = exp((double)gamma_log[p >> 2]);

    if (l < CHUNK) {   // TAB[i] = gamma^{i+1} * (cos,sin)((i+1)theta)
        double a = (double)(l + 1) * th;
        double g = exp(-(double)(l + 1) * ed);
        TAB[((size_t)l*256 + p)*2 + 0] = (float)(g * cos(a));
        TAB[((size_t)l*256 + p)*2 + 1] = (float)(g * sin(a));
    }

    const double a16 = 16.0*th, g16 = exp(-16.0*ed);
    const float Lc = (float)(g16*cos(a16)), Ls = (float)(g16*sin(a16));

    const float* Ep = E + 2*p;
    float2 e0 = *reinterpret_cast<const float2*>(Ep + (size_t)(4*l + 0)*512);
    float2 e1 = *reinterpret_cast<const float2*>(Ep + (size_t)(4*l + 1)*512);
    float2 e2 = *reinterpret_cast<const float2*>(Ep + (size_t)(4*l + 2)*512);
    float2 e3 = *reinterpret_cast<const float2*>(Ep + (size_t)(4*l + 3)*512);

    float2 v = e0;
    v = make_float2(Lc*v.x - Ls*v.y + e1.x, Ls*v.x + Lc*v.y + e1.y);
    v = make_float2(Lc*v.x - Ls*v.y + e2.x, Ls*v.x + Lc*v.y + e2.y);
    v = make_float2(Lc*v.x - Ls*v.y + e3.x, Ls*v.x + Lc*v.y + e3.y);

    #pragma unroll
    for (int d = 0; d < 6; ++d) {
        const int sh = 1 << d;
        const double aa = 64.0 * (double)sh * th;
        const double gg = exp(-64.0 * (double)sh * ed);
        const float Mc = (float)(gg*cos(aa)), Ms = (float)(gg*sin(aa));
        float px = __shfl_up(v.x, sh, 64);
        float py = __shfl_up(v.y, sh, 64);
        if (l >= sh) {
            v.x += Mc*px - Ms*py;
            v.y += Ms*px + Mc*py;
        }
    }

    float sx = __shfl_up(v.x, 1, 64), sy = __shfl_up(v.y, 1, 64);
    float2 s = (l == 0) ? make_float2(0.f, 0.f) : make_float2(sx, sy);
    float* Sp = S + 2*p;
    *reinterpret_cast<float2*>(Sp + (size_t)(4*l + 0)*512) = s;
    s = make_float2(Lc*s.x - Ls*s.y + e0.x, Ls*s.x + Lc*s.y + e0.y);
    *reinterpret_cast<float2*>(Sp + (size_t)(4*l + 1)*512) = s;
    s = make_float2(Lc*s.x - Ls*s.y + e1.x, Ls*s.x + Lc*s.y + e1.y);
    *reinterpret_cast<float2*>(Sp + (size_t)(4*l + 2)*512) = s;
    s = make_float2(Lc*s.x - Ls*s.y + e2.x, Ls*s.x + Lc*s.y + e2.y);
    *reinterpret_cast<float2*>(Sp + (size_t)(4*l + 3)*512) = s;
}

// ---------------------------------------------------------------------------
extern "C" void kernel_launch(void* const* d_in, const int* in_sizes, int n_in,
                              void* d_out, int out_size, void* d_ws, size_t ws_size,
                              hipStream_t stream) {
    const float* X  = (const float*)d_in[0];  // (8,1,512,1,4096); batch 0 = first 2M floats
    const float* th = (const float*)d_in[1];
    const float* P  = (const float*)d_in[2];
    const float* Bm = (const float*)d_in[3];
    const float* C  = (const float*)d_in[4];
    const float* Dv = (const float*)d_in[5];
    const float* gl = (const float*)d_in[6];
    char* wsb = (char*)d_ws;
    float* ws   = (float*)wsb;
    u16*   W1pk = (u16*)(wsb + 32768);
    u16*   CEpk = (u16*)(wsb + 1081344);
    u16*   XTpk = (u16*)(wsb + 2129920);
    float* U    = (float*)(wsb + 10518528);
    float* E    = (float*)(wsb + 18907136);
    float* S    = (float*)(wsb + 19431424);
    float* TAB  = (float*)(wsb + 19955712);
    float* out  = (float*)d_out;

    k_pre<<<576, 256, 0, stream>>>(X, XTpk, P, Bm, th, gl, ws);
    k_proj<<<2048, 256, 0, stream>>>(Bm, C, ws, W1pk, CEpk);
    k_gemm<0><<<512, 256, 0, stream>>>(XTpk, (const float*)0, W1pk, U, XTpk, Dv, ws, E, S, TAB);
    k_carry<<<64, 256, 0, stream>>>(E, S, TAB, th, gl);
    k_gemm<1><<<512, 256, 0, stream>>>((const u16*)0, U, CEpk, out, XTpk, Dv, ws, E, S, TAB);
}